// Round 1
// baseline (23979.237 us; speedup 1.0000x reference)
//
#include <hip/hip_runtime.h>
#include <hip/hip_bf16.h>
#include <cstdint>

// Problem constants (from reference)
constexpr int B_  = 2;
constexpr int S_  = 4096;
constexpr int D_  = 1024;
constexpr int H_  = 16;
constexpr int DH_ = 64;       // head dim
constexpr int DIL = 4;
constexpr int L_  = S_ / DIL; // 1024 (pad == 0 since S % DIL == 0)
constexpr int M_  = B_ * S_;  // 8192 rows

// ---------------------------------------------------------------------------
// LDS tile helpers: 64x64 fp32 tile stored as 16B chunks with XOR swizzle
// chunk' = c4 ^ ((r>>2)&7)  -> b-fragment reads (rows tx*4+j, fixed chunk)
// land on 8 distinct bank-quads (2-way conflict = free per m136), and the
// 16-lane row-major stores are conflict-free.
// ---------------------------------------------------------------------------
__device__ __forceinline__ int swz(int r, int c4) { return c4 ^ ((r >> 2) & 7); }

__device__ __forceinline__ void st4(float* t, int r, int c4, float4 v) {
    *reinterpret_cast<float4*>(t + r * 64 + swz(r, c4) * 4) = v;
}
__device__ __forceinline__ float4 ld4(const float* t, int r, int c4) {
    return *reinterpret_cast<const float4*>(t + r * 64 + swz(r, c4) * 4);
}
__device__ __forceinline__ void st1(float* t, int r, int c, float v) {
    t[r * 64 + swz(r, c >> 2) * 4 + (c & 3)] = v;
}

// ---------------------------------------------------------------------------
// GEMM: C[m,n] = sum_k X[m,k] * W[n,k] + bias[n]   (i.e. X @ W^T + b)
// 64x64 block tile, 4x4 micro-tile, K-tile = 64, float4 inner product.
// ---------------------------------------------------------------------------
__global__ __launch_bounds__(256, 4)
void gemm_xwt(const float* __restrict__ X, const float* __restrict__ W,
              const float* __restrict__ bias, float* __restrict__ C,
              int M, int N, int K) {
    __shared__ float Xs[64 * 64];
    __shared__ float Ws[64 * 64];
    const int tid = threadIdx.x;
    const int tx = tid & 15, ty = tid >> 4;
    const int bm = blockIdx.y * 64, bn = blockIdx.x * 64;

    float acc[4][4] = {};

    for (int k0 = 0; k0 < K; k0 += 64) {
        #pragma unroll
        for (int i = 0; i < 4; ++i) {
            int idx = tid + i * 256;
            int r = idx >> 4, c4 = idx & 15;
            st4(Xs, r, c4,
                *reinterpret_cast<const float4*>(X + (size_t)(bm + r) * K + k0 + c4 * 4));
            st4(Ws, r, c4,
                *reinterpret_cast<const float4*>(W + (size_t)(bn + r) * K + k0 + c4 * 4));
        }
        __syncthreads();
        #pragma unroll
        for (int c4 = 0; c4 < 16; ++c4) {
            float4 a[4], b[4];
            #pragma unroll
            for (int i = 0; i < 4; ++i) a[i] = ld4(Xs, ty * 4 + i, c4);
            #pragma unroll
            for (int j = 0; j < 4; ++j) b[j] = ld4(Ws, tx * 4 + j, c4);
            #pragma unroll
            for (int i = 0; i < 4; ++i)
                #pragma unroll
                for (int j = 0; j < 4; ++j)
                    acc[i][j] += a[i].x * b[j].x + a[i].y * b[j].y +
                                 a[i].z * b[j].z + a[i].w * b[j].w;
        }
        __syncthreads();
    }

    #pragma unroll
    for (int i = 0; i < 4; ++i) {
        int row = bm + ty * 4 + i;
        float4 out;
        out.x = acc[i][0] + bias[bn + tx * 4 + 0];
        out.y = acc[i][1] + bias[bn + tx * 4 + 1];
        out.z = acc[i][2] + bias[bn + tx * 4 + 2];
        out.w = acc[i][3] + bias[bn + tx * 4 + 3];
        *reinterpret_cast<float4*>(C + (size_t)row * N + bn + tx * 4) = out;
    }
}

// ---------------------------------------------------------------------------
// Fused atrous attention: one block = (bd, h, q-tile of 64 rows).
// Row mapping: attention-batch bd = b*4+d, local row l -> global row
// m = b*4096 + l*4 + d. Head h occupies columns [h*64, h*64+64).
// Flash-style online softmax over 16 key tiles of 64.
// ctx is written back into the Q buffer (exclusive element ownership).
// ---------------------------------------------------------------------------
__global__ __launch_bounds__(256, 2)
void attn_fused(const float* __restrict__ Q, const float* __restrict__ K,
                const float* __restrict__ V, float* __restrict__ O) {
    __shared__ float Qs[64 * 64];
    __shared__ float Ks[64 * 64];
    __shared__ float Vt[64 * 64];  // transposed: Vt[dh_col][key]
    __shared__ float Ps[64 * 64];

    const int tid = threadIdx.x;
    const int tx = tid & 15, ty = tid >> 4;
    const int blk = blockIdx.x;
    const int qt = blk & 15;          // 16 q-tiles
    const int h  = (blk >> 4) & 15;   // 16 heads
    const int bd = blk >> 8;          // 8 attention-batches
    const int b  = bd >> 2, dd = bd & 3;
    const size_t rowbase = (size_t)b * S_;
    const int colbase = h * DH_;

    // ---- load Q tile (rows r -> l = qt*64 + r) ----
    #pragma unroll
    for (int i = 0; i < 4; ++i) {
        int idx = tid + i * 256;
        int r = idx >> 4, c4 = idx & 15;
        size_t m = rowbase + (size_t)(qt * 64 + r) * DIL + dd;
        st4(Qs, r, c4,
            *reinterpret_cast<const float4*>(Q + m * D_ + colbase + c4 * 4));
    }

    float m_run[4], l_run[4];
    float o_acc[4][4] = {};
    #pragma unroll
    for (int i = 0; i < 4; ++i) { m_run[i] = -1e30f; l_run[i] = 0.f; }

    for (int kt = 0; kt < L_ / 64; ++kt) {
        // ---- load K tile + V tile (V transposed into Vt) ----
        #pragma unroll
        for (int i = 0; i < 4; ++i) {
            int idx = tid + i * 256;
            int r = idx >> 4, c4 = idx & 15;
            size_t m = rowbase + (size_t)(kt * 64 + r) * DIL + dd;
            st4(Ks, r, c4,
                *reinterpret_cast<const float4*>(K + m * D_ + colbase + c4 * 4));
            float4 v = *reinterpret_cast<const float4*>(V + m * D_ + colbase + c4 * 4);
            st1(Vt, c4 * 4 + 0, r, v.x);
            st1(Vt, c4 * 4 + 1, r, v.y);
            st1(Vt, c4 * 4 + 2, r, v.z);
            st1(Vt, c4 * 4 + 3, r, v.w);
        }
        __syncthreads();

        // ---- GEMM1: scores[r][j] = Q[r] . K[j], scaled by 1/8 ----
        float s[4][4] = {};
        #pragma unroll
        for (int c4 = 0; c4 < 16; ++c4) {
            float4 a[4], bb[4];
            #pragma unroll
            for (int i = 0; i < 4; ++i) a[i]  = ld4(Qs, ty * 4 + i, c4);
            #pragma unroll
            for (int j = 0; j < 4; ++j) bb[j] = ld4(Ks, tx * 4 + j, c4);
            #pragma unroll
            for (int i = 0; i < 4; ++i)
                #pragma unroll
                for (int j = 0; j < 4; ++j)
                    s[i][j] += a[i].x * bb[j].x + a[i].y * bb[j].y +
                               a[i].z * bb[j].z + a[i].w * bb[j].w;
        }

        // ---- online softmax (row r = ty*4+i owned by the 16 tx lanes) ----
        float p[4][4];
        #pragma unroll
        for (int i = 0; i < 4; ++i) {
            float mx = -1e30f;
            #pragma unroll
            for (int j = 0; j < 4; ++j) {
                s[i][j] *= 0.125f;  // 1/sqrt(64)
                mx = fmaxf(mx, s[i][j]);
            }
            #pragma unroll
            for (int o = 1; o < 16; o <<= 1) mx = fmaxf(mx, __shfl_xor(mx, o));
            float m_new = fmaxf(m_run[i], mx);
            float scale = __expf(m_run[i] - m_new);
            float rsum = 0.f;
            #pragma unroll
            for (int j = 0; j < 4; ++j) {
                p[i][j] = __expf(s[i][j] - m_new);
                rsum += p[i][j];
            }
            #pragma unroll
            for (int o = 1; o < 16; o <<= 1) rsum += __shfl_xor(rsum, o);
            l_run[i] = l_run[i] * scale + rsum;
            #pragma unroll
            for (int j = 0; j < 4; ++j) o_acc[i][j] *= scale;
            m_run[i] = m_new;
        }

        // ---- stash P tile ----
        #pragma unroll
        for (int i = 0; i < 4; ++i)
            st4(Ps, ty * 4 + i, tx, make_float4(p[i][0], p[i][1], p[i][2], p[i][3]));
        __syncthreads();

        // ---- GEMM2: o_acc[r][c] += sum_j P[r][j] * V[j][c] ----
        #pragma unroll
        for (int j4 = 0; j4 < 16; ++j4) {
            float4 a[4], bb[4];
            #pragma unroll
            for (int i = 0; i < 4; ++i) a[i]  = ld4(Ps, ty * 4 + i, j4);
            #pragma unroll
            for (int j = 0; j < 4; ++j) bb[j] = ld4(Vt, tx * 4 + j, j4);
            #pragma unroll
            for (int i = 0; i < 4; ++i)
                #pragma unroll
                for (int j = 0; j < 4; ++j)
                    o_acc[i][j] += a[i].x * bb[j].x + a[i].y * bb[j].y +
                                   a[i].z * bb[j].z + a[i].w * bb[j].w;
        }
        __syncthreads();  // before next iteration overwrites Ks/Vt
    }

    // ---- normalize + write ctx (into Q buffer; exclusive ownership) ----
    #pragma unroll
    for (int i = 0; i < 4; ++i) {
        int r = ty * 4 + i;
        size_t m = rowbase + (size_t)(qt * 64 + r) * DIL + dd;
        float inv = 1.f / l_run[i];
        float4 out;
        out.x = o_acc[i][0] * inv;
        out.y = o_acc[i][1] * inv;
        out.z = o_acc[i][2] * inv;
        out.w = o_acc[i][3] * inv;
        *reinterpret_cast<float4*>(O + m * D_ + colbase + tx * 4) = out;
    }
}

// ---------------------------------------------------------------------------
// final = LayerNorm(atted + x) * gamma + beta ; one block per row (D=1024)
// ---------------------------------------------------------------------------
__global__ __launch_bounds__(256)
void add_ln(const float* __restrict__ atted, const float* __restrict__ x,
            const float* __restrict__ gamma, const float* __restrict__ beta,
            float* __restrict__ out) {
    __shared__ float red[8];
    const int tid = threadIdx.x;
    const size_t base = (size_t)blockIdx.x * D_;

    float4 a  = *reinterpret_cast<const float4*>(atted + base + tid * 4);
    float4 xv = *reinterpret_cast<const float4*>(x + base + tid * 4);
    float v0 = a.x + xv.x, v1 = a.y + xv.y, v2 = a.z + xv.z, v3 = a.w + xv.w;

    float s = v0 + v1 + v2 + v3;
    #pragma unroll
    for (int o = 1; o < 64; o <<= 1) s += __shfl_xor(s, o);
    if ((tid & 63) == 0) red[tid >> 6] = s;
    __syncthreads();
    float mean = (red[0] + red[1] + red[2] + red[3]) * (1.0f / D_);

    float d0 = v0 - mean, d1 = v1 - mean, d2 = v2 - mean, d3 = v3 - mean;
    float sq = d0 * d0 + d1 * d1 + d2 * d2 + d3 * d3;
    #pragma unroll
    for (int o = 1; o < 64; o <<= 1) sq += __shfl_xor(sq, o);
    if ((tid & 63) == 0) red[4 + (tid >> 6)] = sq;
    __syncthreads();
    float var = (red[4] + red[5] + red[6] + red[7]) * (1.0f / D_);
    float inv = rsqrtf(var + 1e-5f);

    float4 g = *reinterpret_cast<const float4*>(gamma + tid * 4);
    float4 bb = *reinterpret_cast<const float4*>(beta + tid * 4);
    float4 o4;
    o4.x = d0 * inv * g.x + bb.x;
    o4.y = d1 * inv * g.y + bb.y;
    o4.z = d2 * inv * g.z + bb.z;
    o4.w = d3 * inv * g.w + bb.w;
    *reinterpret_cast<float4*>(out + base + tid * 4) = o4;
}

// ---------------------------------------------------------------------------
extern "C" void kernel_launch(void* const* d_in, const int* in_sizes, int n_in,
                              void* d_out, int out_size, void* d_ws, size_t ws_size,
                              hipStream_t stream) {
    const float* x     = (const float*)d_in[0];
    const float* Wq    = (const float*)d_in[1];
    const float* bq    = (const float*)d_in[2];
    const float* Wk    = (const float*)d_in[3];
    const float* bk    = (const float*)d_in[4];
    const float* Wv    = (const float*)d_in[5];
    const float* bv    = (const float*)d_in[6];
    const float* Wf    = (const float*)d_in[7];
    const float* bf    = (const float*)d_in[8];
    const float* gamma = (const float*)d_in[9];
    const float* beta  = (const float*)d_in[10];

    float* final_out = (float*)d_out;               // (B,S,D) fp32
    float* atted     = final_out + (size_t)M_ * D_; // (B,S,D) fp32

    float* Qb = (float*)d_ws;                       // 3 x 32 MB scratch
    float* Kb = Qb + (size_t)M_ * D_;
    float* Vb = Kb + (size_t)M_ * D_;

    dim3 gemm_grid(D_ / 64, M_ / 64);   // (16, 128)
    gemm_xwt<<<gemm_grid, 256, 0, stream>>>(x, Wq, bq, Qb, M_, D_, D_);
    gemm_xwt<<<gemm_grid, 256, 0, stream>>>(x, Wk, bk, Kb, M_, D_, D_);
    gemm_xwt<<<gemm_grid, 256, 0, stream>>>(x, Wv, bv, Vb, M_, D_, D_);

    // 8 bd * 16 heads * 16 q-tiles = 2048 blocks; ctx overwrites Qb
    attn_fused<<<dim3(DIL * B_ * H_ * (L_ / 64)), 256, 0, stream>>>(Qb, Kb, Vb, Qb);

    gemm_xwt<<<gemm_grid, 256, 0, stream>>>(Qb, Wf, bf, atted, M_, D_, D_);

    add_ln<<<dim3(M_), 256, 0, stream>>>(atted, x, gamma, beta, final_out);
}

// Round 3
// 440.519 us; speedup vs baseline: 54.4341x; 54.4341x over previous
//
#include <hip/hip_runtime.h>
#include <cstdint>
#include <cstddef>

// Problem constants
constexpr int B_  = 2;
constexpr int S_  = 4096;
constexpr int D_  = 1024;
constexpr int H_  = 16;
constexpr int DH_ = 64;
constexpr int DIL = 4;
constexpr int L_  = S_ / DIL;  // 1024
constexpr int M_  = B_ * S_;   // 8192

typedef __attribute__((ext_vector_type(8))) short short8;
typedef __attribute__((ext_vector_type(4))) float f32x4;

__device__ __forceinline__ unsigned short f2b(float f) {
    union { float f; unsigned u; } v;
    v.f = f;
    unsigned r = v.u + 0x7fff + ((v.u >> 16) & 1);   // RNE
    return (unsigned short)(r >> 16);
}

#define GLOAD16(gptr, lptr)                                                    \
    __builtin_amdgcn_global_load_lds(                                          \
        (const __attribute__((address_space(1))) void*)(gptr),                 \
        (__attribute__((address_space(3))) void*)(lptr), 16, 0, 0)

// ---------------------------------------------------------------------------
// fp32 -> bf16 convert (vectorized, exact multiples of 4)
// ---------------------------------------------------------------------------
__global__ __launch_bounds__(256)
void conv_f2b(const float* __restrict__ in, unsigned short* __restrict__ out, int n4) {
    int i = blockIdx.x * 256 + threadIdx.x;
    if (i < n4) {
        float4 v = reinterpret_cast<const float4*>(in)[i];
        ushort4 o;
        o.x = f2b(v.x); o.y = f2b(v.y); o.z = f2b(v.z); o.w = f2b(v.w);
        reinterpret_cast<ushort4*>(out)[i] = o;
    }
}

// ---------------------------------------------------------------------------
// MFMA GEMM: C[m,n] = sum_k A[m,k] * W[n,k] + bias[n]
// m97 structure: BM=BN=128, BK=64, 4 waves (2x2), 4x4 fragments of 16x16x32.
// A: [M][K] bf16 row-major, W: [N][K] bf16 row-major (B^T input).
// OUT_BF16=1 -> write ushort bf16; else fp32.
// ---------------------------------------------------------------------------
template <int OUT_BF16>
__global__ __launch_bounds__(256)
void gemm_mfma(const unsigned short* __restrict__ A,
               const unsigned short* __restrict__ W,
               const float* __restrict__ bias,
               void* __restrict__ Cout, int M, int N, int K) {
    __shared__ unsigned short As[128 * 64];
    __shared__ unsigned short Bs[128 * 64];

    const int tid  = threadIdx.x;
    const int lane = tid & 63, wave = tid >> 6;
    const int l15 = lane & 15, l4 = lane >> 4;
    const int wr = wave >> 1, wc = wave & 1;
    const int bm = blockIdx.y * 128, bn = blockIdx.x * 128;

    f32x4 acc[4][4] = {};

    for (int k0 = 0; k0 < K; k0 += 64) {
        // stage A and B tiles: 1024 16B-chunks each; 4 per thread
        #pragma unroll
        for (int i = 0; i < 4; ++i) {
            int ch = i * 256 + wave * 64 + lane;     // 0..1023
            int r = ch >> 3, c8 = ch & 7;            // row, 16B-chunk in row
            const unsigned short* ga = A + (size_t)(bm + r) * K + k0 + c8 * 8;
            GLOAD16(ga, (char*)As + (size_t)(i * 256 + wave * 64) * 16);
            const unsigned short* gb = W + (size_t)(bn + r) * K + k0 + c8 * 8;
            GLOAD16(gb, (char*)Bs + (size_t)(i * 256 + wave * 64) * 16);
        }
        __syncthreads();   // drains vmcnt before barrier (compiler-emitted)

        #pragma unroll
        for (int ks = 0; ks < 2; ++ks) {
            short8 af[4], bf[4];
            #pragma unroll
            for (int mi = 0; mi < 4; ++mi)
                af[mi] = *reinterpret_cast<const short8*>(
                    &As[(wr * 64 + mi * 16 + l15) * 64 + ks * 32 + l4 * 8]);
            #pragma unroll
            for (int ni = 0; ni < 4; ++ni)
                bf[ni] = *reinterpret_cast<const short8*>(
                    &Bs[(wc * 64 + ni * 16 + l15) * 64 + ks * 32 + l4 * 8]);
            #pragma unroll
            for (int mi = 0; mi < 4; ++mi)
                #pragma unroll
                for (int ni = 0; ni < 4; ++ni)
                    acc[mi][ni] = __builtin_amdgcn_mfma_f32_16x16x32_bf16(
                        af[mi], bf[ni], acc[mi][ni], 0, 0, 0);
        }
        __syncthreads();
    }

    // epilogue: C/D layout col = lane&15, row = (lane>>4)*4 + reg  [m89]
    #pragma unroll
    for (int ni = 0; ni < 4; ++ni) {
        int col = bn + wc * 64 + ni * 16 + l15;
        float bv = bias[col];
        #pragma unroll
        for (int mi = 0; mi < 4; ++mi) {
            #pragma unroll
            for (int r = 0; r < 4; ++r) {
                int row = bm + wr * 64 + mi * 16 + l4 * 4 + r;
                float v = acc[mi][ni][r] + bv;
                if (OUT_BF16)
                    ((unsigned short*)Cout)[(size_t)row * N + col] = f2b(v);
                else
                    ((float*)Cout)[(size_t)row * N + col] = v;
            }
        }
    }
}

// ---------------------------------------------------------------------------
// MFMA flash attention over atrous-permuted rows.
// Block = (qt, h, bd); 4 waves; wave owns 16 q-rows. Q hoisted to registers.
// K staged linear [key][dh] via global_load_lds; V reg-staged transposed
// [dh][key]; P via per-wave-private LDS band (within-wave dep, no barrier).
// ---------------------------------------------------------------------------
__global__ __launch_bounds__(256)
void attn_mfma(const unsigned short* __restrict__ Q,
               const unsigned short* __restrict__ K,
               const unsigned short* __restrict__ V,
               unsigned short* __restrict__ O) {
    __shared__ unsigned short Ks[64 * 64];
    __shared__ unsigned short Vt[64 * 64];
    __shared__ unsigned short Ps[4 * 16 * 64];

    const int tid = threadIdx.x;
    const int lane = tid & 63, wave = tid >> 6;
    const int l15 = lane & 15, l4 = lane >> 4;
    const int blk = blockIdx.x;
    const int qt = blk & 15;
    const int h  = (blk >> 4) & 15;
    const int bd = blk >> 8;
    const int b = bd >> 2, dd = bd & 3;
    const size_t rowbase = (size_t)b * S_;
    const int colbase = h * DH_;

    // Q fragments in registers: A-frag row = l15 (wave band), k = ks*32 + l4*8
    short8 qf[2];
    {
        int q = qt * 64 + wave * 16 + l15;
        const unsigned short* qp =
            Q + (rowbase + (size_t)q * DIL + dd) * D_ + colbase;
        qf[0] = *reinterpret_cast<const short8*>(qp + 0 * 32 + l4 * 8);
        qf[1] = *reinterpret_cast<const short8*>(qp + 1 * 32 + l4 * 8);
    }

    f32x4 o_acc[4] = {};
    float m_run[4], l_run[4];
    #pragma unroll
    for (int r = 0; r < 4; ++r) { m_run[r] = -1e30f; l_run[r] = 0.f; }

    for (int kt = 0; kt < L_ / 64; ++kt) {
        // ---- stage K tile linear [key][dh]: 512 chunks, 2 per thread ----
        #pragma unroll
        for (int i = 0; i < 2; ++i) {
            int ch = i * 256 + wave * 64 + lane;     // 0..511
            int key = ch >> 3, c8 = ch & 7;
            const unsigned short* g =
                K + (rowbase + (size_t)(kt * 64 + key) * DIL + dd) * D_ + colbase + c8 * 8;
            GLOAD16(g, (char*)Ks + (size_t)(i * 256 + wave * 64) * 16);
        }
        // ---- stage V transposed [dh][key] via registers ----
        #pragma unroll
        for (int i = 0; i < 2; ++i) {
            int ch = tid + i * 256;
            int key = ch >> 3, c8 = ch & 7;
            short8 v = *reinterpret_cast<const short8*>(
                V + (rowbase + (size_t)(kt * 64 + key) * DIL + dd) * D_ + colbase + c8 * 8);
            #pragma unroll
            for (int j = 0; j < 8; ++j)
                Vt[(c8 * 8 + j) * 64 + key] = (unsigned short)v[j];
        }
        __syncthreads();

        // ---- QK^T: S[16q][64key] per wave ----
        f32x4 sc[4];
        #pragma unroll
        for (int n = 0; n < 4; ++n) {
            short8 kf0 = *reinterpret_cast<const short8*>(
                &Ks[(n * 16 + l15) * 64 + 0 + l4 * 8]);
            short8 kf1 = *reinterpret_cast<const short8*>(
                &Ks[(n * 16 + l15) * 64 + 32 + l4 * 8]);
            f32x4 z = {0.f, 0.f, 0.f, 0.f};
            z = __builtin_amdgcn_mfma_f32_16x16x32_bf16(qf[0], kf0, z, 0, 0, 0);
            z = __builtin_amdgcn_mfma_f32_16x16x32_bf16(qf[1], kf1, z, 0, 0, 0);
            sc[n] = z * 0.125f;   // 1/sqrt(64)
        }

        // ---- online softmax; row r of lane-group lives in 16 lanes (l4 fixed)
        #pragma unroll
        for (int r = 0; r < 4; ++r) {
            float mx = fmaxf(fmaxf(sc[0][r], sc[1][r]), fmaxf(sc[2][r], sc[3][r]));
            #pragma unroll
            for (int o = 1; o < 16; o <<= 1) mx = fmaxf(mx, __shfl_xor(mx, o));
            float m_new = fmaxf(m_run[r], mx);
            float scale = __expf(m_run[r] - m_new);
            float pr[4], rsum = 0.f;
            #pragma unroll
            for (int n = 0; n < 4; ++n) { pr[n] = __expf(sc[n][r] - m_new); rsum += pr[n]; }
            #pragma unroll
            for (int o = 1; o < 16; o <<= 1) rsum += __shfl_xor(rsum, o);
            l_run[r] = l_run[r] * scale + rsum;
            m_run[r] = m_new;
            #pragma unroll
            for (int n = 0; n < 4; ++n) {
                o_acc[n] *= scale;
                Ps[wave * 1024 + (l4 * 4 + r) * 64 + n * 16 + l15] = f2b(pr[n]);
            }
        }

        // ---- PV: O[16q][64dh] += P(16x64) * V(64x64); within-wave P dep ----
        short8 pa0 = *reinterpret_cast<const short8*>(
            &Ps[wave * 1024 + l15 * 64 + 0 + l4 * 8]);
        short8 pa1 = *reinterpret_cast<const short8*>(
            &Ps[wave * 1024 + l15 * 64 + 32 + l4 * 8]);
        #pragma unroll
        for (int n = 0; n < 4; ++n) {
            short8 vf0 = *reinterpret_cast<const short8*>(
                &Vt[(n * 16 + l15) * 64 + 0 + l4 * 8]);
            short8 vf1 = *reinterpret_cast<const short8*>(
                &Vt[(n * 16 + l15) * 64 + 32 + l4 * 8]);
            o_acc[n] = __builtin_amdgcn_mfma_f32_16x16x32_bf16(pa0, vf0, o_acc[n], 0, 0, 0);
            o_acc[n] = __builtin_amdgcn_mfma_f32_16x16x32_bf16(pa1, vf1, o_acc[n], 0, 0, 0);
        }
        __syncthreads();   // protect Ks/Vt before next stage
    }

    // ---- normalize + write ctx bf16 ----
    #pragma unroll
    for (int r = 0; r < 4; ++r) {
        float inv = 1.f / l_run[r];
        int q = qt * 64 + wave * 16 + l4 * 4 + r;
        unsigned short* op =
            O + (rowbase + (size_t)q * DIL + dd) * D_ + colbase;
        #pragma unroll
        for (int n = 0; n < 4; ++n)
            op[n * 16 + l15] = f2b(o_acc[n][r] * inv);
    }
}

// ---------------------------------------------------------------------------
// final = LayerNorm(atted + x) * gamma + beta ; one block per row (D=1024)
// ---------------------------------------------------------------------------
__global__ __launch_bounds__(256)
void add_ln(const float* __restrict__ atted, const float* __restrict__ x,
            const float* __restrict__ gamma, const float* __restrict__ beta,
            float* __restrict__ out) {
    __shared__ float red[8];
    const int tid = threadIdx.x;
    const size_t base = (size_t)blockIdx.x * D_;

    float4 a  = *reinterpret_cast<const float4*>(atted + base + tid * 4);
    float4 xv = *reinterpret_cast<const float4*>(x + base + tid * 4);
    float v0 = a.x + xv.x, v1 = a.y + xv.y, v2 = a.z + xv.z, v3 = a.w + xv.w;

    float s = v0 + v1 + v2 + v3;
    #pragma unroll
    for (int o = 1; o < 64; o <<= 1) s += __shfl_xor(s, o);
    if ((tid & 63) == 0) red[tid >> 6] = s;
    __syncthreads();
    float mean = (red[0] + red[1] + red[2] + red[3]) * (1.0f / D_);

    float d0 = v0 - mean, d1 = v1 - mean, d2 = v2 - mean, d3 = v3 - mean;
    float sq = d0 * d0 + d1 * d1 + d2 * d2 + d3 * d3;
    #pragma unroll
    for (int o = 1; o < 64; o <<= 1) sq += __shfl_xor(sq, o);
    if ((tid & 63) == 0) red[4 + (tid >> 6)] = sq;
    __syncthreads();
    float var = (red[4] + red[5] + red[6] + red[7]) * (1.0f / D_);
    float inv = rsqrtf(var + 1e-5f);

    float4 g  = *reinterpret_cast<const float4*>(gamma + tid * 4);
    float4 bb = *reinterpret_cast<const float4*>(beta + tid * 4);
    float4 o4;
    o4.x = d0 * inv * g.x + bb.x;
    o4.y = d1 * inv * g.y + bb.y;
    o4.z = d2 * inv * g.z + bb.z;
    o4.w = d3 * inv * g.w + bb.w;
    *reinterpret_cast<float4*>(out + base + tid * 4) = o4;
}

// ---------------------------------------------------------------------------
extern "C" void kernel_launch(void* const* d_in, const int* in_sizes, int n_in,
                              void* d_out, int out_size, void* d_ws, size_t ws_size,
                              hipStream_t stream) {
    const float* x     = (const float*)d_in[0];
    const float* Wq    = (const float*)d_in[1];
    const float* bq    = (const float*)d_in[2];
    const float* Wk    = (const float*)d_in[3];
    const float* bk    = (const float*)d_in[4];
    const float* Wv    = (const float*)d_in[5];
    const float* bv    = (const float*)d_in[6];
    const float* Wf    = (const float*)d_in[7];
    const float* bf    = (const float*)d_in[8];
    const float* gamma = (const float*)d_in[9];
    const float* beta  = (const float*)d_in[10];

    float* final_out = (float*)d_out;               // (B,S,D) fp32
    float* atted     = final_out + (size_t)M_ * D_; // (B,S,D) fp32

    // Workspace (bf16 as ushort): total 75.5 MB (< 100.7 MB proven in R1)
    unsigned short* xb  = (unsigned short*)d_ws;        // also reused as ctxb
    unsigned short* Wqb = xb  + (size_t)M_ * D_;
    unsigned short* Wkb = Wqb + (size_t)D_ * D_;
    unsigned short* Wvb = Wkb + (size_t)D_ * D_;
    unsigned short* Wfb = Wvb + (size_t)D_ * D_;
    unsigned short* Qb  = Wfb + (size_t)D_ * D_;
    unsigned short* Kb  = Qb  + (size_t)M_ * D_;
    unsigned short* Vb  = Kb  + (size_t)M_ * D_;
    unsigned short* ctxb = xb;  // x dead after QKV GEMMs

    // converts
    conv_f2b<<<dim3(M_ * D_ / 4 / 256), 256, 0, stream>>>(x,  xb,  M_ * D_ / 4);
    conv_f2b<<<dim3(D_ * D_ / 4 / 256), 256, 0, stream>>>(Wq, Wqb, D_ * D_ / 4);
    conv_f2b<<<dim3(D_ * D_ / 4 / 256), 256, 0, stream>>>(Wk, Wkb, D_ * D_ / 4);
    conv_f2b<<<dim3(D_ * D_ / 4 / 256), 256, 0, stream>>>(Wv, Wvb, D_ * D_ / 4);
    conv_f2b<<<dim3(D_ * D_ / 4 / 256), 256, 0, stream>>>(Wf, Wfb, D_ * D_ / 4);

    dim3 ggrid(D_ / 128, M_ / 128);   // (8, 64)
    gemm_mfma<1><<<ggrid, 256, 0, stream>>>(xb, Wqb, bq, Qb, M_, D_, D_);
    gemm_mfma<1><<<ggrid, 256, 0, stream>>>(xb, Wkb, bk, Kb, M_, D_, D_);
    gemm_mfma<1><<<ggrid, 256, 0, stream>>>(xb, Wvb, bv, Vb, M_, D_, D_);

    attn_mfma<<<dim3(DIL * B_ * H_ * (L_ / 64)), 256, 0, stream>>>(Qb, Kb, Vb, ctxb);

    gemm_mfma<0><<<ggrid, 256, 0, stream>>>(ctxb, Wfb, bf, atted, M_, D_, D_);

    add_ln<<<dim3(M_), 256, 0, stream>>>(atted, x, gamma, beta, final_out);
}

// Round 5
// 338.141 us; speedup vs baseline: 70.9148x; 1.3028x over previous
//
#include <hip/hip_runtime.h>
#include <cstdint>
#include <cstddef>

// Problem constants
constexpr int B_  = 2;
constexpr int S_  = 4096;
constexpr int D_  = 1024;
constexpr int H_  = 16;
constexpr int DH_ = 64;
constexpr int DIL = 4;
constexpr int L_  = S_ / DIL;  // 1024
constexpr int M_  = B_ * S_;   // 8192

typedef __attribute__((ext_vector_type(8))) short short8;
typedef __attribute__((ext_vector_type(4))) float f32x4;

__device__ __forceinline__ unsigned short f2b(float f) {
    union { float f; unsigned u; } v;
    v.f = f;
    unsigned r = v.u + 0x7fff + ((v.u >> 16) & 1);   // RNE
    return (unsigned short)(r >> 16);
}

#define GLOAD16(gptr, lptr)                                                    \
    __builtin_amdgcn_global_load_lds(                                          \
        (const __attribute__((address_space(1))) void*)(gptr),                 \
        (__attribute__((address_space(3))) void*)(lptr), 16, 0, 0)

// ---------------------------------------------------------------------------
// fp32 -> bf16 convert
// ---------------------------------------------------------------------------
__global__ __launch_bounds__(256)
void conv_f2b(const float* __restrict__ in, unsigned short* __restrict__ out, int n4) {
    int i = blockIdx.x * 256 + threadIdx.x;
    if (i < n4) {
        float4 v = reinterpret_cast<const float4*>(in)[i];
        ushort4 o;
        o.x = f2b(v.x); o.y = f2b(v.y); o.z = f2b(v.z); o.w = f2b(v.w);
        reinterpret_cast<ushort4*>(out)[i] = o;
    }
}

// ---------------------------------------------------------------------------
// MFMA GEMM (m97 structure): C = A @ W^T + bias. BM=BN=128, BK=64, 4 waves.
// ---------------------------------------------------------------------------
template <int OUT_BF16>
__global__ __launch_bounds__(256)
void gemm_mfma(const unsigned short* __restrict__ A,
               const unsigned short* __restrict__ W,
               const float* __restrict__ bias,
               void* __restrict__ Cout, int M, int N, int K) {
    __shared__ unsigned short As[128 * 64];
    __shared__ unsigned short Bs[128 * 64];

    const int tid  = threadIdx.x;
    const int lane = tid & 63, wave = tid >> 6;
    const int l15 = lane & 15, l4 = lane >> 4;
    const int wr = wave >> 1, wc = wave & 1;
    const int bm = blockIdx.y * 128, bn = blockIdx.x * 128;

    f32x4 acc[4][4] = {};

    for (int k0 = 0; k0 < K; k0 += 64) {
        #pragma unroll
        for (int i = 0; i < 4; ++i) {
            int ch = i * 256 + wave * 64 + lane;
            int r = ch >> 3, c8 = ch & 7;
            const unsigned short* ga = A + (size_t)(bm + r) * K + k0 + c8 * 8;
            GLOAD16(ga, (char*)As + (size_t)(i * 256 + wave * 64) * 16);
            const unsigned short* gb = W + (size_t)(bn + r) * K + k0 + c8 * 8;
            GLOAD16(gb, (char*)Bs + (size_t)(i * 256 + wave * 64) * 16);
        }
        __syncthreads();

        #pragma unroll
        for (int ks = 0; ks < 2; ++ks) {
            short8 af[4], bf[4];
            #pragma unroll
            for (int mi = 0; mi < 4; ++mi)
                af[mi] = *reinterpret_cast<const short8*>(
                    &As[(wr * 64 + mi * 16 + l15) * 64 + ks * 32 + l4 * 8]);
            #pragma unroll
            for (int ni = 0; ni < 4; ++ni)
                bf[ni] = *reinterpret_cast<const short8*>(
                    &Bs[(wc * 64 + ni * 16 + l15) * 64 + ks * 32 + l4 * 8]);
            #pragma unroll
            for (int mi = 0; mi < 4; ++mi)
                #pragma unroll
                for (int ni = 0; ni < 4; ++ni)
                    acc[mi][ni] = __builtin_amdgcn_mfma_f32_16x16x32_bf16(
                        af[mi], bf[ni], acc[mi][ni], 0, 0, 0);
        }
        __syncthreads();
    }

    #pragma unroll
    for (int ni = 0; ni < 4; ++ni) {
        int col = bn + wc * 64 + ni * 16 + l15;
        float bv = bias[col];
        #pragma unroll
        for (int mi = 0; mi < 4; ++mi) {
            #pragma unroll
            for (int r = 0; r < 4; ++r) {
                int row = bm + wr * 64 + mi * 16 + l4 * 4 + r;
                float v = acc[mi][ni][r] + bv;
                if (OUT_BF16)
                    ((unsigned short*)Cout)[(size_t)row * N + col] = f2b(v);
                else
                    ((float*)Cout)[(size_t)row * N + col] = v;
            }
        }
    }
}

// ---------------------------------------------------------------------------
// Fused QKV GEMM: W = [Wq;Wk;Wv] contiguous [3072][1024]; routes output
// and bias by 1024-column segment (each 128-col block is within one segment).
// ---------------------------------------------------------------------------
__global__ __launch_bounds__(256)
void gemm_qkv(const unsigned short* __restrict__ A,
              const unsigned short* __restrict__ W,
              const float* __restrict__ bq, const float* __restrict__ bk,
              const float* __restrict__ bv,
              unsigned short* __restrict__ Qb, unsigned short* __restrict__ Kb,
              unsigned short* __restrict__ Vb, int M, int K) {
    __shared__ unsigned short As[128 * 64];
    __shared__ unsigned short Bs[128 * 64];

    const int tid  = threadIdx.x;
    const int lane = tid & 63, wave = tid >> 6;
    const int l15 = lane & 15, l4 = lane >> 4;
    const int wr = wave >> 1, wc = wave & 1;
    const int bm = blockIdx.y * 128, bn = blockIdx.x * 128;

    f32x4 acc[4][4] = {};

    for (int k0 = 0; k0 < K; k0 += 64) {
        #pragma unroll
        for (int i = 0; i < 4; ++i) {
            int ch = i * 256 + wave * 64 + lane;
            int r = ch >> 3, c8 = ch & 7;
            const unsigned short* ga = A + (size_t)(bm + r) * K + k0 + c8 * 8;
            GLOAD16(ga, (char*)As + (size_t)(i * 256 + wave * 64) * 16);
            const unsigned short* gb = W + (size_t)(bn + r) * K + k0 + c8 * 8;
            GLOAD16(gb, (char*)Bs + (size_t)(i * 256 + wave * 64) * 16);
        }
        __syncthreads();

        #pragma unroll
        for (int ks = 0; ks < 2; ++ks) {
            short8 af[4], bf[4];
            #pragma unroll
            for (int mi = 0; mi < 4; ++mi)
                af[mi] = *reinterpret_cast<const short8*>(
                    &As[(wr * 64 + mi * 16 + l15) * 64 + ks * 32 + l4 * 8]);
            #pragma unroll
            for (int ni = 0; ni < 4; ++ni)
                bf[ni] = *reinterpret_cast<const short8*>(
                    &Bs[(wc * 64 + ni * 16 + l15) * 64 + ks * 32 + l4 * 8]);
            #pragma unroll
            for (int mi = 0; mi < 4; ++mi)
                #pragma unroll
                for (int ni = 0; ni < 4; ++ni)
                    acc[mi][ni] = __builtin_amdgcn_mfma_f32_16x16x32_bf16(
                        af[mi], bf[ni], acc[mi][ni], 0, 0, 0);
        }
        __syncthreads();
    }

    const int seg = bn >> 10;                 // 0=Q 1=K 2=V
    const float* bp = (seg == 0) ? bq : (seg == 1) ? bk : bv;
    unsigned short* ob = (seg == 0) ? Qb : (seg == 1) ? Kb : Vb;
    const int cb = bn & 1023;

    #pragma unroll
    for (int ni = 0; ni < 4; ++ni) {
        int col = cb + wc * 64 + ni * 16 + l15;
        float bvv = bp[col];
        #pragma unroll
        for (int mi = 0; mi < 4; ++mi) {
            #pragma unroll
            for (int r = 0; r < 4; ++r) {
                int row = bm + wr * 64 + mi * 16 + l4 * 4 + r;
                ob[(size_t)row * 1024 + col] = f2b(acc[mi][ni][r] + bvv);
            }
        }
    }
}

// ---------------------------------------------------------------------------
// MFMA flash attention, swapped-operand form.
//  S^T = mfma(K, Q)  -> lane (l15,l4) holds S[q=l15][key = n*16+l4*4+r]
//  softmax lane-local over 16 vals + shfl_xor(16,32) cross-l4 reduce
//  P exchanged in-register (16 shfl) into B-fragments
//  O^T = mfma(V^T, P) -> lane holds O[q=l15][dh = nd*16+l4*4+r]
// Ks/Vt XOR-swizzled (chunk ^= row&7): all b128 fragment reads conflict-free.
// K staged via global_load_lds with pre-swizzled source (rule #21);
// V reg-staged with key=lane assignment (transpose writes 2-way = free).
// Double-buffered: kt+1 loads issued before kt compute (T14-lite).
// ---------------------------------------------------------------------------
__global__ __launch_bounds__(256)
void attn_mfma(const unsigned short* __restrict__ Q,
               const unsigned short* __restrict__ K,
               const unsigned short* __restrict__ V,
               unsigned short* __restrict__ O) {
    __shared__ unsigned short Ks[2][64 * 64];   // [key][chunk^ (key&7)]
    __shared__ unsigned short Vt[2][64 * 64];   // V^T [dh][chunk ^ (dh&7)]

    const int tid = threadIdx.x;
    const int lane = tid & 63, wave = tid >> 6;
    const int l15 = lane & 15, l4 = lane >> 4;
    const int blk = blockIdx.x;
    const int qt = blk & 15;
    const int h  = (blk >> 4) & 15;
    const int bd = blk >> 8;
    const int b = bd >> 2, dd = bd & 3;
    const size_t rowbase = (size_t)b * S_;
    const int colbase = h * DH_;

    // Q fragments (B-operand): col q = l15, k = ks*32 + l4*8
    short8 qf[2];
    {
        int q = qt * 64 + wave * 16 + l15;
        const unsigned short* qp =
            Q + (rowbase + (size_t)q * DIL + dd) * D_ + colbase;
        qf[0] = *reinterpret_cast<const short8*>(qp + l4 * 8);
        qf[1] = *reinterpret_cast<const short8*>(qp + 32 + l4 * 8);
    }

    // ---- staging helpers ----
    auto stageK = [&](int kt, int buf) {
        #pragma unroll
        for (int i = 0; i < 2; ++i) {
            int key = i * 32 + wave * 8 + (lane >> 3);
            int srcc = (lane & 7) ^ (lane >> 3);      // pre-swizzled source chunk
            const unsigned short* g =
                K + (rowbase + (size_t)(kt * 64 + key) * DIL + dd) * D_ + colbase + srcc * 8;
            GLOAD16(g, (char*)&Ks[buf][0] + (size_t)(i * 256 + wave * 64) * 16);
        }
    };
    auto loadV = [&](int kt, int i) {
        int c8 = wave * 2 + i;
        return *reinterpret_cast<const short8*>(
            V + (rowbase + (size_t)(kt * 64 + lane) * DIL + dd) * D_ + colbase + c8 * 8);
    };
    auto writeV = [&](int buf, short8 va, short8 vb) {
        #pragma unroll
        for (int i = 0; i < 2; ++i) {
            short8 v = i ? vb : va;
            int c8 = wave * 2 + i;
            #pragma unroll
            for (int j = 0; j < 8; ++j)   // row=c8*8+j, chunk=(lane>>3)^j, off=lane&7
                Vt[buf][(c8 * 8 + j) * 64 + (((lane >> 3) ^ j) * 8) + (lane & 7)] =
                    (unsigned short)v[j];
        }
    };

    f32x4 oT[4] = {};
    float m_run = -1e30f, l_run = 0.f;

    // prologue: stage kt=0
    stageK(0, 0);
    {
        short8 va = loadV(0, 0), vb = loadV(0, 1);
        writeV(0, va, vb);
    }
    __syncthreads();

    const int srcA = ((l4 & 1) * 2) * 16 + l15;
    const int srcB = srcA + 16;
    const bool hi = (l4 & 2) != 0;

    for (int kt = 0; kt < L_ / 64; ++kt) {
        int cur = kt & 1, nxt = cur ^ 1;
        short8 va, vb;
        if (kt < L_ / 64 - 1) {           // issue next-tile loads early (T14)
            stageK(kt + 1, nxt);
            va = loadV(kt + 1, 0);
            vb = loadV(kt + 1, 1);
        }

        // ---- QK^T (S^T form) ----
        f32x4 sT[4];
        #pragma unroll
        for (int n = 0; n < 4; ++n) {
            int row = n * 16 + l15;
            short8 kf0 = *reinterpret_cast<const short8*>(
                &Ks[cur][row * 64 + ((0 * 4 + l4) ^ (l15 & 7)) * 8]);
            short8 kf1 = *reinterpret_cast<const short8*>(
                &Ks[cur][row * 64 + ((1 * 4 + l4) ^ (l15 & 7)) * 8]);
            f32x4 z = {0.f, 0.f, 0.f, 0.f};
            z = __builtin_amdgcn_mfma_f32_16x16x32_bf16(kf0, qf[0], z, 0, 0, 0);
            z = __builtin_amdgcn_mfma_f32_16x16x32_bf16(kf1, qf[1], z, 0, 0, 0);
            sT[n] = z * 0.125f;   // 1/sqrt(64)
        }

        // ---- lane-local online softmax (q = l15) ----
        float mx = -1e30f;
        #pragma unroll
        for (int n = 0; n < 4; ++n)
            #pragma unroll
            for (int r = 0; r < 4; ++r) mx = fmaxf(mx, sT[n][r]);
        mx = fmaxf(mx, __shfl_xor(mx, 16));
        mx = fmaxf(mx, __shfl_xor(mx, 32));
        float m_new = fmaxf(m_run, mx);
        float scale = __expf(m_run - m_new);
        float p[4][4], rsum = 0.f;
        #pragma unroll
        for (int n = 0; n < 4; ++n)
            #pragma unroll
            for (int r = 0; r < 4; ++r) {
                p[n][r] = __expf(sT[n][r] - m_new);
                rsum += p[n][r];
            }
        rsum += __shfl_xor(rsum, 16);
        rsum += __shfl_xor(rsum, 32);
        l_run = l_run * scale + rsum;
        m_run = m_new;
        #pragma unroll
        for (int nd = 0; nd < 4; ++nd) oT[nd] *= scale;

        // ---- pack P to bf16 pairs and exchange into B-fragments ----
        unsigned pk[4][2];
        #pragma unroll
        for (int n = 0; n < 4; ++n) {
            pk[n][0] = (unsigned)f2b(p[n][0]) | ((unsigned)f2b(p[n][1]) << 16);
            pk[n][1] = (unsigned)f2b(p[n][2]) | ((unsigned)f2b(p[n][3]) << 16);
        }
        unsigned exA[4][2], exB[4][2];
        #pragma unroll
        for (int n = 0; n < 4; ++n) {
            #pragma unroll
            for (int d = 0; d < 2; ++d) {
                exA[n][d] = (unsigned)__shfl((int)pk[n][d], srcA);
                exB[n][d] = (unsigned)__shfl((int)pk[n][d], srcB);
            }
        }

        // ---- PV: O^T += V^T . P ----
        #pragma unroll
        for (int ks = 0; ks < 2; ++ks) {
            union { uint4 u; short8 s; } pf;
            pf.u.x = hi ? exA[ks * 2 + 1][0] : exA[ks * 2][0];
            pf.u.y = hi ? exA[ks * 2 + 1][1] : exA[ks * 2][1];
            pf.u.z = hi ? exB[ks * 2 + 1][0] : exB[ks * 2][0];
            pf.u.w = hi ? exB[ks * 2 + 1][1] : exB[ks * 2][1];
            #pragma unroll
            for (int nd = 0; nd < 4; ++nd) {
                int row = nd * 16 + l15;
                short8 vf = *reinterpret_cast<const short8*>(
                    &Vt[cur][row * 64 + ((ks * 4 + l4) ^ (l15 & 7)) * 8]);
                oT[nd] = __builtin_amdgcn_mfma_f32_16x16x32_bf16(vf, pf.s, oT[nd], 0, 0, 0);
            }
        }

        if (kt < L_ / 64 - 1) writeV(nxt, va, vb);
        __syncthreads();   // drains vmcnt (next K tile) + protects buffers
    }

    // ---- epilogue: per-wave LDS transpose band (overlay Ks[0]) ----
    unsigned short* Es = &Ks[0][0];       // 4 waves x 16q x 64dh u16 = 8 KB
    float inv = 1.f / l_run;
    #pragma unroll
    for (int nd = 0; nd < 4; ++nd) {
        unsigned lo = (unsigned)f2b(oT[nd][0] * inv) | ((unsigned)f2b(oT[nd][1] * inv) << 16);
        unsigned hiw = (unsigned)f2b(oT[nd][2] * inv) | ((unsigned)f2b(oT[nd][3] * inv) << 16);
        int chunk = nd * 2 + (l4 >> 1);
        int pc = chunk ^ (l15 & 7);
        uint2 w = make_uint2(lo, hiw);
        *reinterpret_cast<uint2*>(&Es[wave * 1024 + l15 * 64 + pc * 8 + (l4 & 1) * 4]) = w;
    }
    __syncthreads();
    {
        int row = lane >> 2;              // q_local 0..15
        int q = qt * 64 + wave * 16 + row;
        unsigned short* op = O + (rowbase + (size_t)q * DIL + dd) * D_ + colbase;
        #pragma unroll
        for (int i = 0; i < 2; ++i) {
            int c = (lane & 3) * 2 + i;
            int pc = c ^ (row & 7);
            uint4 val = *reinterpret_cast<const uint4*>(&Es[wave * 1024 + row * 64 + pc * 8]);
            *reinterpret_cast<uint4*>(op + c * 8) = val;
        }
    }
}

// ---------------------------------------------------------------------------
// final = LayerNorm(atted + x) * gamma + beta
// ---------------------------------------------------------------------------
__global__ __launch_bounds__(256)
void add_ln(const float* __restrict__ atted, const float* __restrict__ x,
            const float* __restrict__ gamma, const float* __restrict__ beta,
            float* __restrict__ out) {
    __shared__ float red[8];
    const int tid = threadIdx.x;
    const size_t base = (size_t)blockIdx.x * D_;

    float4 a  = *reinterpret_cast<const float4*>(atted + base + tid * 4);
    float4 xv = *reinterpret_cast<const float4*>(x + base + tid * 4);
    float v0 = a.x + xv.x, v1 = a.y + xv.y, v2 = a.z + xv.z, v3 = a.w + xv.w;

    float s = v0 + v1 + v2 + v3;
    #pragma unroll
    for (int o = 1; o < 64; o <<= 1) s += __shfl_xor(s, o);
    if ((tid & 63) == 0) red[tid >> 6] = s;
    __syncthreads();
    float mean = (red[0] + red[1] + red[2] + red[3]) * (1.0f / D_);

    float d0 = v0 - mean, d1 = v1 - mean, d2 = v2 - mean, d3 = v3 - mean;
    float sq = d0 * d0 + d1 * d1 + d2 * d2 + d3 * d3;
    #pragma unroll
    for (int o = 1; o < 64; o <<= 1) sq += __shfl_xor(sq, o);
    if ((tid & 63) == 0) red[4 + (tid >> 6)] = sq;
    __syncthreads();
    float var = (red[4] + red[5] + red[6] + red[7]) * (1.0f / D_);
    float inv = rsqrtf(var + 1e-5f);

    float4 g  = *reinterpret_cast<const float4*>(gamma + tid * 4);
    float4 bb = *reinterpret_cast<const float4*>(beta + tid * 4);
    float4 o4;
    o4.x = d0 * inv * g.x + bb.x;
    o4.y = d1 * inv * g.y + bb.y;
    o4.z = d2 * inv * g.z + bb.z;
    o4.w = d3 * inv * g.w + bb.w;
    *reinterpret_cast<float4*>(out + base + tid * 4) = o4;
}

// ---------------------------------------------------------------------------
extern "C" void kernel_launch(void* const* d_in, const int* in_sizes, int n_in,
                              void* d_out, int out_size, void* d_ws, size_t ws_size,
                              hipStream_t stream) {
    const float* x     = (const float*)d_in[0];
    const float* Wq    = (const float*)d_in[1];
    const float* bq    = (const float*)d_in[2];
    const float* Wk    = (const float*)d_in[3];
    const float* bk    = (const float*)d_in[4];
    const float* Wv    = (const float*)d_in[5];
    const float* bv    = (const float*)d_in[6];
    const float* Wf    = (const float*)d_in[7];
    const float* bf    = (const float*)d_in[8];
    const float* gamma = (const float*)d_in[9];
    const float* beta  = (const float*)d_in[10];

    float* final_out = (float*)d_out;               // (B,S,D) fp32
    float* atted     = final_out + (size_t)M_ * D_; // (B,S,D) fp32

    // Workspace (bf16 as ushort): Wq/Wk/Wv contiguous -> fused QKV GEMM
    unsigned short* xb  = (unsigned short*)d_ws;    // reused as ctxb after QKV
    unsigned short* Wqb = xb  + (size_t)M_ * D_;
    unsigned short* Wkb = Wqb + (size_t)D_ * D_;
    unsigned short* Wvb = Wkb + (size_t)D_ * D_;
    unsigned short* Wfb = Wvb + (size_t)D_ * D_;
    unsigned short* Qb  = Wfb + (size_t)D_ * D_;
    unsigned short* Kb  = Qb  + (size_t)M_ * D_;
    unsigned short* Vb  = Kb  + (size_t)M_ * D_;
    unsigned short* ctxb = xb;

    conv_f2b<<<dim3(M_ * D_ / 4 / 256), 256, 0, stream>>>(x,  xb,  M_ * D_ / 4);
    conv_f2b<<<dim3(D_ * D_ / 4 / 256), 256, 0, stream>>>(Wq, Wqb, D_ * D_ / 4);
    conv_f2b<<<dim3(D_ * D_ / 4 / 256), 256, 0, stream>>>(Wk, Wkb, D_ * D_ / 4);
    conv_f2b<<<dim3(D_ * D_ / 4 / 256), 256, 0, stream>>>(Wv, Wvb, D_ * D_ / 4);
    conv_f2b<<<dim3(D_ * D_ / 4 / 256), 256, 0, stream>>>(Wf, Wfb, D_ * D_ / 4);

    // fused QKV: N = 3072
    gemm_qkv<<<dim3(3072 / 128, M_ / 128), 256, 0, stream>>>(
        xb, Wqb, bq, bk, bv, Qb, Kb, Vb, M_, D_);

    attn_mfma<<<dim3(DIL * B_ * H_ * (L_ / 64)), 256, 0, stream>>>(Qb, Kb, Vb, ctxb);

    gemm_mfma<0><<<dim3(D_ / 128, M_ / 128), 256, 0, stream>>>(
        ctxb, Wfb, bf, atted, M_, D_, D_);

    add_ln<<<dim3(M_), 256, 0, stream>>>(atted, x, gamma, beta, final_out);
}

// Round 7
// 322.459 us; speedup vs baseline: 74.3637x; 1.0486x over previous
//
#include <hip/hip_runtime.h>
#include <hip/hip_bf16.h>
#include <cstdint>
#include <cstddef>

// Problem constants
constexpr int B_  = 2;
constexpr int S_  = 4096;
constexpr int D_  = 1024;
constexpr int H_  = 16;
constexpr int DH_ = 64;
constexpr int DIL = 4;
constexpr int L_  = S_ / DIL;  // 1024
constexpr int M_  = B_ * S_;   // 8192

typedef __attribute__((ext_vector_type(8))) short short8;
typedef __attribute__((ext_vector_type(4))) float f32x4;

__device__ __forceinline__ unsigned short f2b(float f) {
    union { float f; unsigned u; } v;
    v.f = f;
    unsigned r = v.u + 0x7fff + ((v.u >> 16) & 1);   // RNE
    return (unsigned short)(r >> 16);
}

__device__ __forceinline__ unsigned pkbf(float a, float b) {
    float2 t; t.x = a; t.y = b;
    __hip_bfloat162 h = __float22bfloat162_rn(t);    // v_cvt_pk_bf16_f32
    union { __hip_bfloat162 h; unsigned u; } c; c.h = h;
    return c.u;
}

// m204 bijective XCD swizzle (8 XCDs)
__device__ __forceinline__ int xcd_swz(int orig, int nwg) {
    int q = nwg >> 3, r = nwg & 7;
    int xcd = orig & 7, idx = orig >> 3;
    return (xcd < r ? xcd * (q + 1) : r * (q + 1) + (xcd - r) * q) + idx;
}

#define GLOAD16(gptr, lptr)                                                    \
    __builtin_amdgcn_global_load_lds(                                          \
        (const __attribute__((address_space(1))) void*)(gptr),                 \
        (__attribute__((address_space(3))) void*)(lptr), 16, 0, 0)

// ---------------------------------------------------------------------------
// fp32 -> bf16 converts
// ---------------------------------------------------------------------------
__global__ __launch_bounds__(256)
void conv_f2b(const float* __restrict__ in, unsigned short* __restrict__ out, int n4) {
    int i = blockIdx.x * 256 + threadIdx.x;
    if (i < n4) {
        float4 v = reinterpret_cast<const float4*>(in)[i];
        ushort4 o;
        o.x = f2b(v.x); o.y = f2b(v.y); o.z = f2b(v.z); o.w = f2b(v.w);
        reinterpret_cast<ushort4*>(out)[i] = o;
    }
}

// all four weight matrices in one launch (1024 blocks each)
__global__ __launch_bounds__(256)
void conv_w4(const float* __restrict__ w0, const float* __restrict__ w1,
             const float* __restrict__ w2, const float* __restrict__ w3,
             unsigned short* __restrict__ out) {
    int bid = blockIdx.x;
    int which = bid >> 10;
    const float* src = (which == 0) ? w0 : (which == 1) ? w1 : (which == 2) ? w2 : w3;
    int i = (bid & 1023) * 256 + threadIdx.x;
    float4 v = reinterpret_cast<const float4*>(src)[i];
    ushort4 o;
    o.x = f2b(v.x); o.y = f2b(v.y); o.z = f2b(v.z); o.w = f2b(v.w);
    reinterpret_cast<ushort4*>(out + (size_t)which * D_ * D_)[i] = o;
}

// ---------------------------------------------------------------------------
// MFMA GEMM (m97 structure): C = A @ W^T + bias. BM=BN=128, BK=64, 4 waves.
// 1D grid with XCD swizzle; bn-major chunks (consecutive wg share bn panel).
// ---------------------------------------------------------------------------
template <int OUT_BF16>
__global__ __launch_bounds__(256)
void gemm_mfma(const unsigned short* __restrict__ A,
               const unsigned short* __restrict__ W,
               const float* __restrict__ bias,
               void* __restrict__ Cout, int M, int N, int K) {
    __shared__ unsigned short As[128 * 64];
    __shared__ unsigned short Bs[128 * 64];

    const int tid  = threadIdx.x;
    const int lane = tid & 63, wave = tid >> 6;
    const int l15 = lane & 15, l4 = lane >> 4;
    const int wr = wave >> 1, wc = wave & 1;
    const int gy = M >> 7;
    const int wg = xcd_swz(blockIdx.x, gridDim.x);
    const int bm = (wg % gy) * 128, bn = (wg / gy) * 128;

    f32x4 acc[4][4] = {};

    for (int k0 = 0; k0 < K; k0 += 64) {
        #pragma unroll
        for (int i = 0; i < 4; ++i) {
            int ch = i * 256 + wave * 64 + lane;
            int r = ch >> 3, c8 = ch & 7;
            const unsigned short* ga = A + (size_t)(bm + r) * K + k0 + c8 * 8;
            GLOAD16(ga, (char*)As + (size_t)(i * 256 + wave * 64) * 16);
            const unsigned short* gb = W + (size_t)(bn + r) * K + k0 + c8 * 8;
            GLOAD16(gb, (char*)Bs + (size_t)(i * 256 + wave * 64) * 16);
        }
        __syncthreads();

        #pragma unroll
        for (int ks = 0; ks < 2; ++ks) {
            short8 af[4], bf[4];
            #pragma unroll
            for (int mi = 0; mi < 4; ++mi)
                af[mi] = *reinterpret_cast<const short8*>(
                    &As[(wr * 64 + mi * 16 + l15) * 64 + ks * 32 + l4 * 8]);
            #pragma unroll
            for (int ni = 0; ni < 4; ++ni)
                bf[ni] = *reinterpret_cast<const short8*>(
                    &Bs[(wc * 64 + ni * 16 + l15) * 64 + ks * 32 + l4 * 8]);
            #pragma unroll
            for (int mi = 0; mi < 4; ++mi)
                #pragma unroll
                for (int ni = 0; ni < 4; ++ni)
                    acc[mi][ni] = __builtin_amdgcn_mfma_f32_16x16x32_bf16(
                        af[mi], bf[ni], acc[mi][ni], 0, 0, 0);
        }
        __syncthreads();
    }

    #pragma unroll
    for (int ni = 0; ni < 4; ++ni) {
        int col = bn + wc * 64 + ni * 16 + l15;
        float bv = bias[col];
        #pragma unroll
        for (int mi = 0; mi < 4; ++mi) {
            #pragma unroll
            for (int r = 0; r < 4; ++r) {
                int row = bm + wr * 64 + mi * 16 + l4 * 4 + r;
                float v = acc[mi][ni][r] + bv;
                if (OUT_BF16)
                    ((unsigned short*)Cout)[(size_t)row * N + col] = f2b(v);
                else
                    ((float*)Cout)[(size_t)row * N + col] = v;
            }
        }
    }
}

// ---------------------------------------------------------------------------
// Fused QKV GEMM: W = [Wq;Wk;Wv] contiguous [3072][1024]
// ---------------------------------------------------------------------------
__global__ __launch_bounds__(256)
void gemm_qkv(const unsigned short* __restrict__ A,
              const unsigned short* __restrict__ W,
              const float* __restrict__ bq, const float* __restrict__ bk,
              const float* __restrict__ bv,
              unsigned short* __restrict__ Qb, unsigned short* __restrict__ Kb,
              unsigned short* __restrict__ Vb, int M, int K) {
    __shared__ unsigned short As[128 * 64];
    __shared__ unsigned short Bs[128 * 64];

    const int tid  = threadIdx.x;
    const int lane = tid & 63, wave = tid >> 6;
    const int l15 = lane & 15, l4 = lane >> 4;
    const int wr = wave >> 1, wc = wave & 1;
    const int gy = M >> 7;
    const int wg = xcd_swz(blockIdx.x, gridDim.x);
    const int bm = (wg % gy) * 128, bn = (wg / gy) * 128;

    f32x4 acc[4][4] = {};

    for (int k0 = 0; k0 < K; k0 += 64) {
        #pragma unroll
        for (int i = 0; i < 4; ++i) {
            int ch = i * 256 + wave * 64 + lane;
            int r = ch >> 3, c8 = ch & 7;
            const unsigned short* ga = A + (size_t)(bm + r) * K + k0 + c8 * 8;
            GLOAD16(ga, (char*)As + (size_t)(i * 256 + wave * 64) * 16);
            const unsigned short* gb = W + (size_t)(bn + r) * K + k0 + c8 * 8;
            GLOAD16(gb, (char*)Bs + (size_t)(i * 256 + wave * 64) * 16);
        }
        __syncthreads();

        #pragma unroll
        for (int ks = 0; ks < 2; ++ks) {
            short8 af[4], bf[4];
            #pragma unroll
            for (int mi = 0; mi < 4; ++mi)
                af[mi] = *reinterpret_cast<const short8*>(
                    &As[(wr * 64 + mi * 16 + l15) * 64 + ks * 32 + l4 * 8]);
            #pragma unroll
            for (int ni = 0; ni < 4; ++ni)
                bf[ni] = *reinterpret_cast<const short8*>(
                    &Bs[(wc * 64 + ni * 16 + l15) * 64 + ks * 32 + l4 * 8]);
            #pragma unroll
            for (int mi = 0; mi < 4; ++mi)
                #pragma unroll
                for (int ni = 0; ni < 4; ++ni)
                    acc[mi][ni] = __builtin_amdgcn_mfma_f32_16x16x32_bf16(
                        af[mi], bf[ni], acc[mi][ni], 0, 0, 0);
        }
        __syncthreads();
    }

    const int seg = bn >> 10;                 // 0=Q 1=K 2=V
    const float* bp = (seg == 0) ? bq : (seg == 1) ? bk : bv;
    unsigned short* ob = (seg == 0) ? Qb : (seg == 1) ? Kb : Vb;
    const int cb = bn & 1023;

    #pragma unroll
    for (int ni = 0; ni < 4; ++ni) {
        int col = cb + wc * 64 + ni * 16 + l15;
        float bvv = bp[col];
        #pragma unroll
        for (int mi = 0; mi < 4; ++mi) {
            #pragma unroll
            for (int r = 0; r < 4; ++r) {
                int row = bm + wr * 64 + mi * 16 + l4 * 4 + r;
                ob[(size_t)row * 1024 + col] = f2b(acc[mi][ni][r] + bvv);
            }
        }
    }
}

// ---------------------------------------------------------------------------
// V transpose prepass: Vb [m][1024] bf16 -> Vtg [(bd*16+h)*64 + dh][L] bf16.
// One block = (bd, h, 64-key tile). Done ONCE (attention previously
// re-transposed every (bd,h) slice 16x inside the hot loop).
// ---------------------------------------------------------------------------
__global__ __launch_bounds__(256)
void tvt(const unsigned short* __restrict__ Vb, unsigned short* __restrict__ Vtg) {
    __shared__ unsigned short Ts[64 * 64];
    const int tid = threadIdx.x;
    const int blk = blockIdx.x;
    const int lt = blk & 15;
    const int h  = (blk >> 4) & 15;
    const int bd = blk >> 8;
    const int b = bd >> 2, dd = bd & 3;
    const size_t rowbase = (size_t)b * S_;

    // load 64 keys x 64 dh, store transposed (chunk-swizzled)
    #pragma unroll
    for (int i = 0; i < 2; ++i) {
        int ch = i * 256 + tid;
        int lloc = ch >> 3, c8 = ch & 7;
        short8 v = *reinterpret_cast<const short8*>(
            Vb + (rowbase + (size_t)(lt * 64 + lloc) * DIL + dd) * D_ + h * 64 + c8 * 8);
        #pragma unroll
        for (int j = 0; j < 8; ++j) {
            int dh = c8 * 8 + j;
            Ts[dh * 64 + (((lloc >> 3) ^ (dh & 7)) * 8) + (lloc & 7)] = (unsigned short)v[j];
        }
    }
    __syncthreads();

    // write out rows of V^T, coalesced
    const size_t obase = ((size_t)(bd * 16 + h) * 64) * L_;
    #pragma unroll
    for (int i = 0; i < 2; ++i) {
        int ch = i * 256 + tid;
        int dh = ch >> 3, c = ch & 7;
        uint4 val = *reinterpret_cast<const uint4*>(&Ts[dh * 64 + ((c ^ (dh & 7)) * 8)]);
        *reinterpret_cast<uint4*>(Vtg + obase + (size_t)dh * L_ + lt * 64 + c * 8) = val;
    }
}

// ---------------------------------------------------------------------------
// MFMA flash attention, swapped-operand form.
//  S^T = mfma(K, Q); softmax lane-local (q=l15) + shfl_xor(16,32)
//  P -> per-wave swizzled LDS band (4x ds_write_b64, 2x ds_read_b128)
//  O^T = mfma(V^T, P); V^T staged directly via global_load_lds from Vtg
// K and V^T tiles XOR-swizzled (chunk ^= row&7), pre-swizzled global source.
// Double-buffered: kt+1 staging issued before kt compute.
// ---------------------------------------------------------------------------
__global__ __launch_bounds__(256)
void attn_mfma(const unsigned short* __restrict__ Q,
               const unsigned short* __restrict__ K,
               const unsigned short* __restrict__ Vtg,
               unsigned short* __restrict__ O) {
    __shared__ unsigned short Ks[2][64 * 64];   // [key][chunk ^ (key&7)]
    __shared__ unsigned short Vs[2][64 * 64];   // V^T [dh][chunk ^ (dh&7)]
    __shared__ unsigned short Ps[4][1024];      // per-wave P band [q=16][key=64]

    const int tid = threadIdx.x;
    const int lane = tid & 63, wave = tid >> 6;
    const int l15 = lane & 15, l4 = lane >> 4;
    const int blk = xcd_swz(blockIdx.x, gridDim.x);
    const int qt = blk & 15;
    const int h  = (blk >> 4) & 15;
    const int bd = blk >> 8;
    const int b = bd >> 2, dd = bd & 3;
    const size_t rowbase = (size_t)b * S_;
    const int colbase = h * DH_;

    // Q fragments (B-operand): col q = l15, k = ks*32 + l4*8
    short8 qf[2];
    {
        int q = qt * 64 + wave * 16 + l15;
        const unsigned short* qp =
            Q + (rowbase + (size_t)q * DIL + dd) * D_ + colbase;
        qf[0] = *reinterpret_cast<const short8*>(qp + l4 * 8);
        qf[1] = *reinterpret_cast<const short8*>(qp + 32 + l4 * 8);
    }

    const unsigned short* vbase = Vtg + ((size_t)(bd * 16 + h) * 64) * L_;

    auto stageK = [&](int kt, int buf) {
        #pragma unroll
        for (int i = 0; i < 2; ++i) {
            int key = i * 32 + wave * 8 + (lane >> 3);
            int srcc = (lane & 7) ^ (lane >> 3);      // pre-swizzled source chunk
            const unsigned short* g =
                K + (rowbase + (size_t)(kt * 64 + key) * DIL + dd) * D_ + colbase + srcc * 8;
            GLOAD16(g, (char*)&Ks[buf][0] + (size_t)(i * 256 + wave * 64) * 16);
        }
    };
    auto stageV = [&](int kt, int buf) {
        #pragma unroll
        for (int i = 0; i < 2; ++i) {
            int dh = i * 32 + wave * 8 + (lane >> 3);
            int srcc = (lane & 7) ^ (lane >> 3);
            const unsigned short* g = vbase + (size_t)dh * L_ + kt * 64 + srcc * 8;
            GLOAD16(g, (char*)&Vs[buf][0] + (size_t)(i * 256 + wave * 64) * 16);
        }
    };

    f32x4 oT[4] = {};
    float m_run = -1e30f, l_run = 0.f;

    stageK(0, 0);
    stageV(0, 0);
    __syncthreads();

    constexpr int NT = L_ / 64;
    for (int kt = 0; kt < NT; ++kt) {
        int cur = kt & 1, nxt = cur ^ 1;
        if (kt < NT - 1) {                 // issue next-tile staging early
            stageK(kt + 1, nxt);
            stageV(kt + 1, nxt);
        }

        // ---- QK^T (S^T form): lane holds S[q=l15][key = n*16 + l4*4 + r] ----
        f32x4 sT[4];
        #pragma unroll
        for (int n = 0; n < 4; ++n) {
            int row = n * 16 + l15;
            short8 kf0 = *reinterpret_cast<const short8*>(
                &Ks[cur][row * 64 + ((0 * 4 + l4) ^ (l15 & 7)) * 8]);
            short8 kf1 = *reinterpret_cast<const short8*>(
                &Ks[cur][row * 64 + ((1 * 4 + l4) ^ (l15 & 7)) * 8]);
            f32x4 z = {0.f, 0.f, 0.f, 0.f};
            z = __builtin_amdgcn_mfma_f32_16x16x32_bf16(kf0, qf[0], z, 0, 0, 0);
            z = __builtin_amdgcn_mfma_f32_16x16x32_bf16(kf1, qf[1], z, 0, 0, 0);
            sT[n] = z * 0.125f;   // 1/sqrt(64)
        }

        // ---- lane-local online softmax (q = l15) ----
        float mx = -1e30f;
        #pragma unroll
        for (int n = 0; n < 4; ++n)
            #pragma unroll
            for (int r = 0; r < 4; ++r) mx = fmaxf(mx, sT[n][r]);
        mx = fmaxf(mx, __shfl_xor(mx, 16));
        mx = fmaxf(mx, __shfl_xor(mx, 32));
        float m_new = fmaxf(m_run, mx);
        float scale = __expf(m_run - m_new);
        float p[4][4], rsum = 0.f;
        #pragma unroll
        for (int n = 0; n < 4; ++n)
            #pragma unroll
            for (int r = 0; r < 4; ++r) {
                p[n][r] = __expf(sT[n][r] - m_new);
                rsum += p[n][r];
            }
        rsum += __shfl_xor(rsum, 16);
        rsum += __shfl_xor(rsum, 32);
        l_run = l_run * scale + rsum;
        m_run = m_new;
        #pragma unroll
        for (int nd = 0; nd < 4; ++nd) oT[nd] *= scale;

        // ---- P -> per-wave swizzled LDS band (keys n*16+l4*4..+3 @ q=l15) ----
        #pragma unroll
        for (int n = 0; n < 4; ++n) {
            uint2 w;
            w.x = pkbf(p[n][0], p[n][1]);
            w.y = pkbf(p[n][2], p[n][3]);
            int c = n * 2 + (l4 >> 1);
            int pc = c ^ (l15 & 7);
            *reinterpret_cast<uint2*>(&Ps[wave][l15 * 64 + pc * 8 + (l4 & 1) * 4]) = w;
        }
        // B-fragments: keys ks*32 + l4*8 + {0..7} at col q=l15 (within-wave dep)
        short8 pb0 = *reinterpret_cast<const short8*>(
            &Ps[wave][l15 * 64 + ((0 * 4 + l4) ^ (l15 & 7)) * 8]);
        short8 pb1 = *reinterpret_cast<const short8*>(
            &Ps[wave][l15 * 64 + ((1 * 4 + l4) ^ (l15 & 7)) * 8]);

        // ---- PV: O^T += V^T . P ----
        #pragma unroll
        for (int ks = 0; ks < 2; ++ks) {
            short8 pb = ks ? pb1 : pb0;
            #pragma unroll
            for (int nd = 0; nd < 4; ++nd) {
                short8 vf = *reinterpret_cast<const short8*>(
                    &Vs[cur][(nd * 16 + l15) * 64 + ((ks * 4 + l4) ^ (l15 & 7)) * 8]);
                oT[nd] = __builtin_amdgcn_mfma_f32_16x16x32_bf16(vf, pb, oT[nd], 0, 0, 0);
            }
        }

        __syncthreads();   // next-tile staging complete + buffers protected
    }

    // ---- epilogue: per-wave transpose band (reuse Ps) + coalesced store ----
    unsigned short* Es = &Ps[0][0];
    float inv = 1.f / l_run;
    #pragma unroll
    for (int nd = 0; nd < 4; ++nd) {
        uint2 w;
        w.x = pkbf(oT[nd][0] * inv, oT[nd][1] * inv);
        w.y = pkbf(oT[nd][2] * inv, oT[nd][3] * inv);
        int chunk = nd * 2 + (l4 >> 1);
        int pc = chunk ^ (l15 & 7);
        *reinterpret_cast<uint2*>(&Es[wave * 1024 + l15 * 64 + pc * 8 + (l4 & 1) * 4]) = w;
    }
    __syncthreads();
    {
        int row = lane >> 2;              // q_local 0..15
        int q = qt * 64 + wave * 16 + row;
        unsigned short* op = O + (rowbase + (size_t)q * DIL + dd) * D_ + colbase;
        #pragma unroll
        for (int i = 0; i < 2; ++i) {
            int c = (lane & 3) * 2 + i;
            int pc = c ^ (row & 7);
            uint4 val = *reinterpret_cast<const uint4*>(&Es[wave * 1024 + row * 64 + pc * 8]);
            *reinterpret_cast<uint4*>(op + c * 8) = val;
        }
    }
}

// ---------------------------------------------------------------------------
// final = LayerNorm(atted + x) * gamma + beta
// ---------------------------------------------------------------------------
__global__ __launch_bounds__(256)
void add_ln(const float* __restrict__ atted, const float* __restrict__ x,
            const float* __restrict__ gamma, const float* __restrict__ beta,
            float* __restrict__ out) {
    __shared__ float red[8];
    const int tid = threadIdx.x;
    const size_t base = (size_t)blockIdx.x * D_;

    float4 a  = *reinterpret_cast<const float4*>(atted + base + tid * 4);
    float4 xv = *reinterpret_cast<const float4*>(x + base + tid * 4);
    float v0 = a.x + xv.x, v1 = a.y + xv.y, v2 = a.z + xv.z, v3 = a.w + xv.w;

    float s = v0 + v1 + v2 + v3;
    #pragma unroll
    for (int o = 1; o < 64; o <<= 1) s += __shfl_xor(s, o);
    if ((tid & 63) == 0) red[tid >> 6] = s;
    __syncthreads();
    float mean = (red[0] + red[1] + red[2] + red[3]) * (1.0f / D_);

    float d0 = v0 - mean, d1 = v1 - mean, d2 = v2 - mean, d3 = v3 - mean;
    float sq = d0 * d0 + d1 * d1 + d2 * d2 + d3 * d3;
    #pragma unroll
    for (int o = 1; o < 64; o <<= 1) sq += __shfl_xor(sq, o);
    if ((tid & 63) == 0) red[4 + (tid >> 6)] = sq;
    __syncthreads();
    float var = (red[4] + red[5] + red[6] + red[7]) * (1.0f / D_);
    float inv = rsqrtf(var + 1e-5f);

    float4 g  = *reinterpret_cast<const float4*>(gamma + tid * 4);
    float4 bb = *reinterpret_cast<const float4*>(beta + tid * 4);
    float4 o4;
    o4.x = d0 * inv * g.x + bb.x;
    o4.y = d1 * inv * g.y + bb.y;
    o4.z = d2 * inv * g.z + bb.z;
    o4.w = d3 * inv * g.w + bb.w;
    *reinterpret_cast<float4*>(out + base + tid * 4) = o4;
}

// ---------------------------------------------------------------------------
extern "C" void kernel_launch(void* const* d_in, const int* in_sizes, int n_in,
                              void* d_out, int out_size, void* d_ws, size_t ws_size,
                              hipStream_t stream) {
    const float* x     = (const float*)d_in[0];
    const float* Wq    = (const float*)d_in[1];
    const float* bq    = (const float*)d_in[2];
    const float* Wk    = (const float*)d_in[3];
    const float* bk    = (const float*)d_in[4];
    const float* Wv    = (const float*)d_in[5];
    const float* bv    = (const float*)d_in[6];
    const float* Wf    = (const float*)d_in[7];
    const float* bf    = (const float*)d_in[8];
    const float* gamma = (const float*)d_in[9];
    const float* beta  = (const float*)d_in[10];

    float* final_out = (float*)d_out;               // (B,S,D) fp32
    float* atted     = final_out + (size_t)M_ * D_; // (B,S,D) fp32

    // Workspace (bf16): 16 + 8 + 48 + 16 = 88 MB (<100.7 MB proven in R1)
    unsigned short* xb  = (unsigned short*)d_ws;    // reused as ctxb after QKV
    unsigned short* Wqb = xb  + (size_t)M_ * D_;
    unsigned short* Wkb = Wqb + (size_t)D_ * D_;
    unsigned short* Wvb = Wkb + (size_t)D_ * D_;
    unsigned short* Wfb = Wvb + (size_t)D_ * D_;
    unsigned short* Qb  = Wfb + (size_t)D_ * D_;
    unsigned short* Kb  = Qb  + (size_t)M_ * D_;
    unsigned short* Vb  = Kb  + (size_t)M_ * D_;
    unsigned short* Vtg = Vb  + (size_t)M_ * D_;    // [(bd*16+h)*64+dh][L]
    unsigned short* ctxb = xb;

    conv_f2b<<<dim3(M_ * D_ / 4 / 256), 256, 0, stream>>>(x, xb, M_ * D_ / 4);
    conv_w4<<<dim3(4096), 256, 0, stream>>>(Wq, Wk, Wv, Wf, Wqb);

    gemm_qkv<<<dim3((3072 / 128) * (M_ / 128)), 256, 0, stream>>>(
        xb, Wqb, bq, bk, bv, Qb, Kb, Vb, M_, D_);

    tvt<<<dim3(DIL * B_ * H_ * (L_ / 64)), 256, 0, stream>>>(Vb, Vtg);

    attn_mfma<<<dim3(DIL * B_ * H_ * (L_ / 64)), 256, 0, stream>>>(Qb, Kb, Vtg, ctxb);

    gemm_mfma<0><<<dim3((D_ / 128) * (M_ / 128)), 256, 0, stream>>>(
        ctxb, Wfb, bf, atted, M_, D_, D_);

    add_ln<<<dim3(M_), 256, 0, stream>>>(atted, x, gamma, beta, final_out);
}

// Round 8
// 317.094 us; speedup vs baseline: 75.6220x; 1.0169x over previous
//
#include <hip/hip_runtime.h>
#include <hip/hip_bf16.h>
#include <cstdint>
#include <cstddef>

// Problem constants
constexpr int B_  = 2;
constexpr int S_  = 4096;
constexpr int D_  = 1024;
constexpr int H_  = 16;
constexpr int DH_ = 64;
constexpr int DIL = 4;
constexpr int L_  = S_ / DIL;  // 1024
constexpr int M_  = B_ * S_;   // 8192

typedef __attribute__((ext_vector_type(8))) short short8;
typedef __attribute__((ext_vector_type(4))) float f32x4;

__device__ __forceinline__ unsigned short f2b(float f) {
    union { float f; unsigned u; } v;
    v.f = f;
    unsigned r = v.u + 0x7fff + ((v.u >> 16) & 1);   // RNE
    return (unsigned short)(r >> 16);
}

__device__ __forceinline__ unsigned pkbf(float a, float b) {
    float2 t; t.x = a; t.y = b;
    __hip_bfloat162 h = __float22bfloat162_rn(t);    // v_cvt_pk_bf16_f32
    union { __hip_bfloat162 h; unsigned u; } c; c.h = h;
    return c.u;
}

// m204 bijective XCD swizzle (8 XCDs)
__device__ __forceinline__ int xcd_swz(int orig, int nwg) {
    int q = nwg >> 3, r = nwg & 7;
    int xcd = orig & 7, idx = orig >> 3;
    return (xcd < r ? xcd * (q + 1) : r * (q + 1) + (xcd - r) * q) + idx;
}

#define GLOAD16(gptr, lptr)                                                    \
    __builtin_amdgcn_global_load_lds(                                          \
        (const __attribute__((address_space(1))) void*)(gptr),                 \
        (__attribute__((address_space(3))) void*)(lptr), 16, 0, 0)

// ---------------------------------------------------------------------------
// fp32 -> bf16 converts
// ---------------------------------------------------------------------------
__global__ __launch_bounds__(256)
void conv_f2b(const float* __restrict__ in, unsigned short* __restrict__ out, int n4) {
    int i = blockIdx.x * 256 + threadIdx.x;
    if (i < n4) {
        float4 v = reinterpret_cast<const float4*>(in)[i];
        ushort4 o;
        o.x = f2b(v.x); o.y = f2b(v.y); o.z = f2b(v.z); o.w = f2b(v.w);
        reinterpret_cast<ushort4*>(out)[i] = o;
    }
}

// all four weight matrices in one launch (1024 blocks each)
__global__ __launch_bounds__(256)
void conv_w4(const float* __restrict__ w0, const float* __restrict__ w1,
             const float* __restrict__ w2, const float* __restrict__ w3,
             unsigned short* __restrict__ out) {
    int bid = blockIdx.x;
    int which = bid >> 10;
    const float* src = (which == 0) ? w0 : (which == 1) ? w1 : (which == 2) ? w2 : w3;
    int i = (bid & 1023) * 256 + threadIdx.x;
    float4 v = reinterpret_cast<const float4*>(src)[i];
    ushort4 o;
    o.x = f2b(v.x); o.y = f2b(v.y); o.z = f2b(v.z); o.w = f2b(v.w);
    reinterpret_cast<ushort4*>(out + (size_t)which * D_ * D_)[i] = o;
}

// ---------------------------------------------------------------------------
// MFMA GEMM (m97 structure): C = A @ W^T + bias. BM=BN=128, BK=64, 4 waves.
// bn-FAST mapping: each XCD's contiguous chunk spans few bm panels x all bn
// -> per-XCD A working set (2 MB) is L2-resident; W streams via L3.
// ---------------------------------------------------------------------------
template <int OUT_BF16>
__global__ __launch_bounds__(256)
void gemm_mfma(const unsigned short* __restrict__ A,
               const unsigned short* __restrict__ W,
               const float* __restrict__ bias,
               void* __restrict__ Cout, int M, int N, int K) {
    __shared__ unsigned short As[128 * 64];
    __shared__ unsigned short Bs[128 * 64];

    const int tid  = threadIdx.x;
    const int lane = tid & 63, wave = tid >> 6;
    const int l15 = lane & 15, l4 = lane >> 4;
    const int wr = wave >> 1, wc = wave & 1;
    const int gx = N >> 7;
    const int wg = xcd_swz(blockIdx.x, gridDim.x);
    const int bm = (wg / gx) * 128, bn = (wg % gx) * 128;

    f32x4 acc[4][4] = {};

    for (int k0 = 0; k0 < K; k0 += 64) {
        #pragma unroll
        for (int i = 0; i < 4; ++i) {
            int ch = i * 256 + wave * 64 + lane;
            int r = ch >> 3, c8 = ch & 7;
            const unsigned short* ga = A + (size_t)(bm + r) * K + k0 + c8 * 8;
            GLOAD16(ga, (char*)As + (size_t)(i * 256 + wave * 64) * 16);
            const unsigned short* gb = W + (size_t)(bn + r) * K + k0 + c8 * 8;
            GLOAD16(gb, (char*)Bs + (size_t)(i * 256 + wave * 64) * 16);
        }
        __syncthreads();

        #pragma unroll
        for (int ks = 0; ks < 2; ++ks) {
            short8 af[4], bf[4];
            #pragma unroll
            for (int mi = 0; mi < 4; ++mi)
                af[mi] = *reinterpret_cast<const short8*>(
                    &As[(wr * 64 + mi * 16 + l15) * 64 + ks * 32 + l4 * 8]);
            #pragma unroll
            for (int ni = 0; ni < 4; ++ni)
                bf[ni] = *reinterpret_cast<const short8*>(
                    &Bs[(wc * 64 + ni * 16 + l15) * 64 + ks * 32 + l4 * 8]);
            #pragma unroll
            for (int mi = 0; mi < 4; ++mi)
                #pragma unroll
                for (int ni = 0; ni < 4; ++ni)
                    acc[mi][ni] = __builtin_amdgcn_mfma_f32_16x16x32_bf16(
                        af[mi], bf[ni], acc[mi][ni], 0, 0, 0);
        }
        __syncthreads();
    }

    #pragma unroll
    for (int ni = 0; ni < 4; ++ni) {
        int col = bn + wc * 64 + ni * 16 + l15;
        float bv = bias[col];
        #pragma unroll
        for (int mi = 0; mi < 4; ++mi) {
            #pragma unroll
            for (int r = 0; r < 4; ++r) {
                int row = bm + wr * 64 + mi * 16 + l4 * 4 + r;
                float v = acc[mi][ni][r] + bv;
                if (OUT_BF16)
                    ((unsigned short*)Cout)[(size_t)row * N + col] = f2b(v);
                else
                    ((float*)Cout)[(size_t)row * N + col] = v;
            }
        }
    }
}

// ---------------------------------------------------------------------------
// Fused QKV GEMM: W = [Wq;Wk;Wv] contiguous [3072][1024]; bn-fast mapping.
// Q segment is pre-scaled by 1/sqrt(dh) = 0.125 (exact pow2) so attention
// skips the score scale.
// ---------------------------------------------------------------------------
__global__ __launch_bounds__(256)
void gemm_qkv(const unsigned short* __restrict__ A,
              const unsigned short* __restrict__ W,
              const float* __restrict__ bq, const float* __restrict__ bk,
              const float* __restrict__ bv,
              unsigned short* __restrict__ Qb, unsigned short* __restrict__ Kb,
              unsigned short* __restrict__ Vb, int M, int K) {
    __shared__ unsigned short As[128 * 64];
    __shared__ unsigned short Bs[128 * 64];

    const int tid  = threadIdx.x;
    const int lane = tid & 63, wave = tid >> 6;
    const int l15 = lane & 15, l4 = lane >> 4;
    const int wr = wave >> 1, wc = wave & 1;
    const int gx = 24;   // 3072 / 128
    const int wg = xcd_swz(blockIdx.x, gridDim.x);
    const int bm = (wg / gx) * 128, bn = (wg % gx) * 128;

    f32x4 acc[4][4] = {};

    for (int k0 = 0; k0 < K; k0 += 64) {
        #pragma unroll
        for (int i = 0; i < 4; ++i) {
            int ch = i * 256 + wave * 64 + lane;
            int r = ch >> 3, c8 = ch & 7;
            const unsigned short* ga = A + (size_t)(bm + r) * K + k0 + c8 * 8;
            GLOAD16(ga, (char*)As + (size_t)(i * 256 + wave * 64) * 16);
            const unsigned short* gb = W + (size_t)(bn + r) * K + k0 + c8 * 8;
            GLOAD16(gb, (char*)Bs + (size_t)(i * 256 + wave * 64) * 16);
        }
        __syncthreads();

        #pragma unroll
        for (int ks = 0; ks < 2; ++ks) {
            short8 af[4], bf[4];
            #pragma unroll
            for (int mi = 0; mi < 4; ++mi)
                af[mi] = *reinterpret_cast<const short8*>(
                    &As[(wr * 64 + mi * 16 + l15) * 64 + ks * 32 + l4 * 8]);
            #pragma unroll
            for (int ni = 0; ni < 4; ++ni)
                bf[ni] = *reinterpret_cast<const short8*>(
                    &Bs[(wc * 64 + ni * 16 + l15) * 64 + ks * 32 + l4 * 8]);
            #pragma unroll
            for (int mi = 0; mi < 4; ++mi)
                #pragma unroll
                for (int ni = 0; ni < 4; ++ni)
                    acc[mi][ni] = __builtin_amdgcn_mfma_f32_16x16x32_bf16(
                        af[mi], bf[ni], acc[mi][ni], 0, 0, 0);
        }
        __syncthreads();
    }

    const int seg = bn >> 10;                 // 0=Q 1=K 2=V
    const float* bp = (seg == 0) ? bq : (seg == 1) ? bk : bv;
    unsigned short* ob = (seg == 0) ? Qb : (seg == 1) ? Kb : Vb;
    const float qs = (seg == 0) ? 0.125f : 1.0f;   // fold 1/sqrt(dh) into Q
    const int cb = bn & 1023;

    #pragma unroll
    for (int ni = 0; ni < 4; ++ni) {
        int col = cb + wc * 64 + ni * 16 + l15;
        float bvv = bp[col];
        #pragma unroll
        for (int mi = 0; mi < 4; ++mi) {
            #pragma unroll
            for (int r = 0; r < 4; ++r) {
                int row = bm + wr * 64 + mi * 16 + l4 * 4 + r;
                ob[(size_t)row * 1024 + col] = f2b((acc[mi][ni][r] + bvv) * qs);
            }
        }
    }
}

// ---------------------------------------------------------------------------
// V transpose prepass: Vb [m][1024] bf16 -> Vtg [(bd*16+h)*64 + dh][L] bf16.
// ---------------------------------------------------------------------------
__global__ __launch_bounds__(256)
void tvt(const unsigned short* __restrict__ Vb, unsigned short* __restrict__ Vtg) {
    __shared__ unsigned short Ts[64 * 64];
    const int tid = threadIdx.x;
    const int blk = blockIdx.x;
    const int lt = blk & 15;
    const int h  = (blk >> 4) & 15;
    const int bd = blk >> 8;
    const int b = bd >> 2, dd = bd & 3;
    const size_t rowbase = (size_t)b * S_;

    #pragma unroll
    for (int i = 0; i < 2; ++i) {
        int ch = i * 256 + tid;
        int lloc = ch >> 3, c8 = ch & 7;
        short8 v = *reinterpret_cast<const short8*>(
            Vb + (rowbase + (size_t)(lt * 64 + lloc) * DIL + dd) * D_ + h * 64 + c8 * 8);
        #pragma unroll
        for (int j = 0; j < 8; ++j) {
            int dh = c8 * 8 + j;
            Ts[dh * 64 + (((lloc >> 3) ^ (dh & 7)) * 8) + (lloc & 7)] = (unsigned short)v[j];
        }
    }
    __syncthreads();

    const size_t obase = ((size_t)(bd * 16 + h) * 64) * L_;
    #pragma unroll
    for (int i = 0; i < 2; ++i) {
        int ch = i * 256 + tid;
        int dh = ch >> 3, c = ch & 7;
        uint4 val = *reinterpret_cast<const uint4*>(&Ts[dh * 64 + ((c ^ (dh & 7)) * 8)]);
        *reinterpret_cast<uint4*>(Vtg + obase + (size_t)dh * L_ + lt * 64 + c * 8) = val;
    }
}

// ---------------------------------------------------------------------------
// MFMA flash attention, swapped-operand form (Q pre-scaled by 0.125).
// ---------------------------------------------------------------------------
__global__ __launch_bounds__(256)
void attn_mfma(const unsigned short* __restrict__ Q,
               const unsigned short* __restrict__ K,
               const unsigned short* __restrict__ Vtg,
               unsigned short* __restrict__ O) {
    __shared__ unsigned short Ks[2][64 * 64];   // [key][chunk ^ (key&7)]
    __shared__ unsigned short Vs[2][64 * 64];   // V^T [dh][chunk ^ (dh&7)]
    __shared__ unsigned short Ps[4][1024];      // per-wave P band [q=16][key=64]

    const int tid = threadIdx.x;
    const int lane = tid & 63, wave = tid >> 6;
    const int l15 = lane & 15, l4 = lane >> 4;
    const int blk = xcd_swz(blockIdx.x, gridDim.x);
    const int qt = blk & 15;
    const int h  = (blk >> 4) & 15;
    const int bd = blk >> 8;
    const int b = bd >> 2, dd = bd & 3;
    const size_t rowbase = (size_t)b * S_;
    const int colbase = h * DH_;

    short8 qf[2];
    {
        int q = qt * 64 + wave * 16 + l15;
        const unsigned short* qp =
            Q + (rowbase + (size_t)q * DIL + dd) * D_ + colbase;
        qf[0] = *reinterpret_cast<const short8*>(qp + l4 * 8);
        qf[1] = *reinterpret_cast<const short8*>(qp + 32 + l4 * 8);
    }

    const unsigned short* vbase = Vtg + ((size_t)(bd * 16 + h) * 64) * L_;

    auto stageK = [&](int kt, int buf) {
        #pragma unroll
        for (int i = 0; i < 2; ++i) {
            int key = i * 32 + wave * 8 + (lane >> 3);
            int srcc = (lane & 7) ^ (lane >> 3);      // pre-swizzled source chunk
            const unsigned short* g =
                K + (rowbase + (size_t)(kt * 64 + key) * DIL + dd) * D_ + colbase + srcc * 8;
            GLOAD16(g, (char*)&Ks[buf][0] + (size_t)(i * 256 + wave * 64) * 16);
        }
    };
    auto stageV = [&](int kt, int buf) {
        #pragma unroll
        for (int i = 0; i < 2; ++i) {
            int dh = i * 32 + wave * 8 + (lane >> 3);
            int srcc = (lane & 7) ^ (lane >> 3);
            const unsigned short* g = vbase + (size_t)dh * L_ + kt * 64 + srcc * 8;
            GLOAD16(g, (char*)&Vs[buf][0] + (size_t)(i * 256 + wave * 64) * 16);
        }
    };

    f32x4 oT[4] = {};
    float m_run = -1e30f, l_run = 0.f;

    stageK(0, 0);
    stageV(0, 0);
    __syncthreads();

    constexpr int NT = L_ / 64;
    for (int kt = 0; kt < NT; ++kt) {
        int cur = kt & 1, nxt = cur ^ 1;
        if (kt < NT - 1) {                 // issue next-tile staging early
            stageK(kt + 1, nxt);
            stageV(kt + 1, nxt);
        }

        // ---- QK^T (S^T form): lane holds S[q=l15][key = n*16 + l4*4 + r] ----
        f32x4 sT[4];
        #pragma unroll
        for (int n = 0; n < 4; ++n) {
            int row = n * 16 + l15;
            short8 kf0 = *reinterpret_cast<const short8*>(
                &Ks[cur][row * 64 + ((0 * 4 + l4) ^ (l15 & 7)) * 8]);
            short8 kf1 = *reinterpret_cast<const short8*>(
                &Ks[cur][row * 64 + ((1 * 4 + l4) ^ (l15 & 7)) * 8]);
            f32x4 z = {0.f, 0.f, 0.f, 0.f};
            z = __builtin_amdgcn_mfma_f32_16x16x32_bf16(kf0, qf[0], z, 0, 0, 0);
            z = __builtin_amdgcn_mfma_f32_16x16x32_bf16(kf1, qf[1], z, 0, 0, 0);
            sT[n] = z;   // Q pre-scaled by 1/sqrt(dh)
        }

        // ---- lane-local online softmax (q = l15) ----
        float mx = -1e30f;
        #pragma unroll
        for (int n = 0; n < 4; ++n)
            #pragma unroll
            for (int r = 0; r < 4; ++r) mx = fmaxf(mx, sT[n][r]);
        mx = fmaxf(mx, __shfl_xor(mx, 16));
        mx = fmaxf(mx, __shfl_xor(mx, 32));
        float m_new = fmaxf(m_run, mx);
        float scale = __expf(m_run - m_new);
        float p[4][4], rsum = 0.f;
        #pragma unroll
        for (int n = 0; n < 4; ++n)
            #pragma unroll
            for (int r = 0; r < 4; ++r) {
                p[n][r] = __expf(sT[n][r] - m_new);
                rsum += p[n][r];
            }
        rsum += __shfl_xor(rsum, 16);
        rsum += __shfl_xor(rsum, 32);
        l_run = l_run * scale + rsum;
        m_run = m_new;
        #pragma unroll
        for (int nd = 0; nd < 4; ++nd) oT[nd] *= scale;

        // ---- P -> per-wave swizzled LDS band ----
        #pragma unroll
        for (int n = 0; n < 4; ++n) {
            uint2 w;
            w.x = pkbf(p[n][0], p[n][1]);
            w.y = pkbf(p[n][2], p[n][3]);
            int c = n * 2 + (l4 >> 1);
            int pc = c ^ (l15 & 7);
            *reinterpret_cast<uint2*>(&Ps[wave][l15 * 64 + pc * 8 + (l4 & 1) * 4]) = w;
        }
        short8 pb0 = *reinterpret_cast<const short8*>(
            &Ps[wave][l15 * 64 + ((0 * 4 + l4) ^ (l15 & 7)) * 8]);
        short8 pb1 = *reinterpret_cast<const short8*>(
            &Ps[wave][l15 * 64 + ((1 * 4 + l4) ^ (l15 & 7)) * 8]);

        // ---- PV: O^T += V^T . P ----
        #pragma unroll
        for (int ks = 0; ks < 2; ++ks) {
            short8 pb = ks ? pb1 : pb0;
            #pragma unroll
            for (int nd = 0; nd < 4; ++nd) {
                short8 vf = *reinterpret_cast<const short8*>(
                    &Vs[cur][(nd * 16 + l15) * 64 + ((ks * 4 + l4) ^ (l15 & 7)) * 8]);
                oT[nd] = __builtin_amdgcn_mfma_f32_16x16x32_bf16(vf, pb, oT[nd], 0, 0, 0);
            }
        }

        __syncthreads();   // next-tile staging complete + buffers protected
    }

    // ---- epilogue: per-wave transpose band (reuse Ps) + coalesced store ----
    unsigned short* Es = &Ps[0][0];
    float inv = 1.f / l_run;
    #pragma unroll
    for (int nd = 0; nd < 4; ++nd) {
        uint2 w;
        w.x = pkbf(oT[nd][0] * inv, oT[nd][1] * inv);
        w.y = pkbf(oT[nd][2] * inv, oT[nd][3] * inv);
        int chunk = nd * 2 + (l4 >> 1);
        int pc = chunk ^ (l15 & 7);
        *reinterpret_cast<uint2*>(&Es[wave * 1024 + l15 * 64 + pc * 8 + (l4 & 1) * 4]) = w;
    }
    __syncthreads();
    {
        int row = lane >> 2;              // q_local 0..15
        int q = qt * 64 + wave * 16 + row;
        unsigned short* op = O + (rowbase + (size_t)q * DIL + dd) * D_ + colbase;
        #pragma unroll
        for (int i = 0; i < 2; ++i) {
            int c = (lane & 3) * 2 + i;
            int pc = c ^ (row & 7);
            uint4 val = *reinterpret_cast<const uint4*>(&Es[wave * 1024 + row * 64 + pc * 8]);
            *reinterpret_cast<uint4*>(op + c * 8) = val;
        }
    }
}

// ---------------------------------------------------------------------------
// final = LayerNorm(atted + x) * gamma + beta
// ---------------------------------------------------------------------------
__global__ __launch_bounds__(256)
void add_ln(const float* __restrict__ atted, const float* __restrict__ x,
            const float* __restrict__ gamma, const float* __restrict__ beta,
            float* __restrict__ out) {
    __shared__ float red[8];
    const int tid = threadIdx.x;
    const size_t base = (size_t)blockIdx.x * D_;

    float4 a  = *reinterpret_cast<const float4*>(atted + base + tid * 4);
    float4 xv = *reinterpret_cast<const float4*>(x + base + tid * 4);
    float v0 = a.x + xv.x, v1 = a.y + xv.y, v2 = a.z + xv.z, v3 = a.w + xv.w;

    float s = v0 + v1 + v2 + v3;
    #pragma unroll
    for (int o = 1; o < 64; o <<= 1) s += __shfl_xor(s, o);
    if ((tid & 63) == 0) red[tid >> 6] = s;
    __syncthreads();
    float mean = (red[0] + red[1] + red[2] + red[3]) * (1.0f / D_);

    float d0 = v0 - mean, d1 = v1 - mean, d2 = v2 - mean, d3 = v3 - mean;
    float sq = d0 * d0 + d1 * d1 + d2 * d2 + d3 * d3;
    #pragma unroll
    for (int o = 1; o < 64; o <<= 1) sq += __shfl_xor(sq, o);
    if ((tid & 63) == 0) red[4 + (tid >> 6)] = sq;
    __syncthreads();
    float var = (red[4] + red[5] + red[6] + red[7]) * (1.0f / D_);
    float inv = rsqrtf(var + 1e-5f);

    float4 g  = *reinterpret_cast<const float4*>(gamma + tid * 4);
    float4 bb = *reinterpret_cast<const float4*>(beta + tid * 4);
    float4 o4;
    o4.x = d0 * inv * g.x + bb.x;
    o4.y = d1 * inv * g.y + bb.y;
    o4.z = d2 * inv * g.z + bb.z;
    o4.w = d3 * inv * g.w + bb.w;
    *reinterpret_cast<float4*>(out + base + tid * 4) = o4;
}

// ---------------------------------------------------------------------------
extern "C" void kernel_launch(void* const* d_in, const int* in_sizes, int n_in,
                              void* d_out, int out_size, void* d_ws, size_t ws_size,
                              hipStream_t stream) {
    const float* x     = (const float*)d_in[0];
    const float* Wq    = (const float*)d_in[1];
    const float* bq    = (const float*)d_in[2];
    const float* Wk    = (const float*)d_in[3];
    const float* bk    = (const float*)d_in[4];
    const float* Wv    = (const float*)d_in[5];
    const float* bv    = (const float*)d_in[6];
    const float* Wf    = (const float*)d_in[7];
    const float* bf    = (const float*)d_in[8];
    const float* gamma = (const float*)d_in[9];
    const float* beta  = (const float*)d_in[10];

    float* final_out = (float*)d_out;               // (B,S,D) fp32
    float* atted     = final_out + (size_t)M_ * D_; // (B,S,D) fp32

    // Workspace (bf16): 16 + 8 + 48 + 16 = 88 MB (<100.7 MB proven in R1)
    unsigned short* xb  = (unsigned short*)d_ws;    // reused as ctxb after QKV
    unsigned short* Wqb = xb  + (size_t)M_ * D_;
    unsigned short* Wkb = Wqb + (size_t)D_ * D_;
    unsigned short* Wvb = Wkb + (size_t)D_ * D_;
    unsigned short* Wfb = Wvb + (size_t)D_ * D_;
    unsigned short* Qb  = Wfb + (size_t)D_ * D_;
    unsigned short* Kb  = Qb  + (size_t)M_ * D_;
    unsigned short* Vb  = Kb  + (size_t)M_ * D_;
    unsigned short* Vtg = Vb  + (size_t)M_ * D_;    // [(bd*16+h)*64+dh][L]
    unsigned short* ctxb = xb;

    conv_f2b<<<dim3(M_ * D_ / 4 / 256), 256, 0, stream>>>(x, xb, M_ * D_ / 4);
    conv_w4<<<dim3(4096), 256, 0, stream>>>(Wq, Wk, Wv, Wf, Wqb);

    gemm_qkv<<<dim3((3072 / 128) * (M_ / 128)), 256, 0, stream>>>(
        xb, Wqb, bq, bk, bv, Qb, Kb, Vb, M_, D_);

    tvt<<<dim3(DIL * B_ * H_ * (L_ / 64)), 256, 0, stream>>>(Vb, Vtg);

    attn_mfma<<<dim3(DIL * B_ * H_ * (L_ / 64)), 256, 0, stream>>>(Qb, Kb, Vtg, ctxb);

    gemm_mfma<0><<<dim3((D_ / 128) * (M_ / 128)), 256, 0, stream>>>(
        ctxb, Wfb, bf, atted, M_, D_, D_);

    add_ln<<<dim3(M_), 256, 0, stream>>>(atted, x, gamma, beta, final_out);
}